// Round 1
// baseline (7937.851 us; speedup 1.0000x reference)
//
#include <hip/hip_runtime.h>

#define BB   64
#define PP   196
#define ENCD 2048
#define DECD 512
#define VV   10000
#define TT   21

__device__ __forceinline__ float sigm(float x)   { return 1.f / (1.f + __expf(-x)); }
__device__ __forceinline__ float tanh_f(float x) { return 1.f - 2.f / (1.f + __expf(2.f * x)); }

// ---------------- setup kernels ----------------

// mean over P: mean[b,e] = (1/196) sum_p enc[b,p,e]
__global__ void k_mean(const float* __restrict__ enc, float* __restrict__ mean) {
    int idx = blockIdx.x * 256 + threadIdx.x;      // 64*2048 = 131072
    int b = idx >> 11, e = idx & 2047;
    const float* p = enc + (size_t)b * PP * ENCD + e;
    float s = 0.f;
    #pragma unroll 4
    for (int i = 0; i < PP; ++i) s += p[(size_t)i * ENCD];
    mean[idx] = s * (1.f / 196.f);
}

// h0/c0 = mean_enc @ W_inith/c + bias
__global__ void k_inithc(const float* __restrict__ mean,
                         const float* __restrict__ Wh, const float* __restrict__ bh,
                         const float* __restrict__ Wc, const float* __restrict__ bc,
                         float* __restrict__ h, float* __restrict__ c) {
    int idx = blockIdx.x * 256 + threadIdx.x;      // 64*512 = 32768
    int b = idx >> 9, d = idx & 511;
    const float* m = mean + b * ENCD;
    float ah = 0.f, ac = 0.f;
    #pragma unroll 4
    for (int e = 0; e < ENCD; ++e) {
        float mv = m[e];
        ah += mv * Wh[(size_t)e * DECD + d];
        ac += mv * Wc[(size_t)e * DECD + d];
    }
    h[idx] = ah + bh[d];
    c[idx] = ac + bc[d];
}

// att1 = encoder_out @ W_enc + b_enc   (12544 x 2048) @ (2048 x 512)
__global__ __launch_bounds__(256) void k_att1(const float* __restrict__ A,
                                              const float* __restrict__ W,
                                              const float* __restrict__ bias,
                                              float* __restrict__ C) {
    __shared__ float As[16][128];
    __shared__ float Bs[16][128];
    const int m0 = blockIdx.y * 128;
    const int n0 = blockIdx.x * 128;
    const int tid = threadIdx.x;
    const int tx = tid & 15, ty = tid >> 4;
    float acc[8][8] = {};
    const int am = tid >> 2;              // 0..63
    const int ak = (tid & 3) * 4;         // 0,4,8,12
    const int bk = tid >> 5;              // 0..7
    const int bn = (tid & 31) * 4;

    for (int k0 = 0; k0 < 2048; k0 += 16) {
        #pragma unroll
        for (int pass = 0; pass < 2; ++pass) {
            int m = am + pass * 64;
            float4 v = *(const float4*)(A + (size_t)(m0 + m) * 2048 + k0 + ak);
            As[ak + 0][m] = v.x; As[ak + 1][m] = v.y;
            As[ak + 2][m] = v.z; As[ak + 3][m] = v.w;
        }
        #pragma unroll
        for (int pass = 0; pass < 2; ++pass) {
            int k = bk + pass * 8;
            float4 v = *(const float4*)(W + (size_t)(k0 + k) * 512 + n0 + bn);
            *(float4*)&Bs[k][bn] = v;
        }
        __syncthreads();
        #pragma unroll
        for (int kk = 0; kk < 16; ++kk) {
            float4 a0 = *(const float4*)&As[kk][ty * 8];
            float4 a1 = *(const float4*)&As[kk][ty * 8 + 4];
            float4 b0 = *(const float4*)&Bs[kk][tx * 8];
            float4 b1 = *(const float4*)&Bs[kk][tx * 8 + 4];
            float av[8] = {a0.x, a0.y, a0.z, a0.w, a1.x, a1.y, a1.z, a1.w};
            float bv[8] = {b0.x, b0.y, b0.z, b0.w, b1.x, b1.y, b1.z, b1.w};
            #pragma unroll
            for (int i = 0; i < 8; ++i)
                #pragma unroll
                for (int j = 0; j < 8; ++j) acc[i][j] += av[i] * bv[j];
        }
        __syncthreads();
    }
    #pragma unroll
    for (int i = 0; i < 8; ++i) {
        int row = m0 + ty * 8 + i;
        #pragma unroll
        for (int j = 0; j < 8; ++j) {
            int col = n0 + tx * 8 + j;
            C[(size_t)row * 512 + col] = acc[i][j] + bias[col];
        }
    }
}

__global__ void k_declen(const int* __restrict__ lens, float* __restrict__ out) {
    int b = threadIdx.x;
    if (b < BB) out[b] = (float)(lens[b] - 1);
}

// ---------------- per-step kernels ----------------

// att2 = h@W_dec + b_dec (n<512); gate = sigmoid(h@W_beta + b_beta) (n>=512)
__global__ void k_att2gate(const float* __restrict__ h,
                           const float* __restrict__ Wd, const float* __restrict__ bd,
                           const float* __restrict__ Wb, const float* __restrict__ bb,
                           float* __restrict__ att2, float* __restrict__ gate) {
    int idx = blockIdx.x * 256 + threadIdx.x;  // 64*2560
    int b = idx / 2560, n = idx % 2560;
    const float* hr = h + b * DECD;
    if (n < 512) {
        float a = bd[n];
        #pragma unroll 4
        for (int d = 0; d < 512; ++d) a += hr[d] * Wd[(size_t)d * 512 + n];
        att2[b * 512 + n] = a;
    } else {
        int n2 = n - 512;
        float a = bb[n2];
        #pragma unroll 4
        for (int d = 0; d < 512; ++d) a += hr[d] * Wb[(size_t)d * 2048 + n2];
        gate[b * 2048 + n2] = sigm(a);
    }
}

// e scores + softmax -> alpha (one block per b)
__global__ __launch_bounds__(256) void k_escore(const float* __restrict__ att1,
                                                const float* __restrict__ att2,
                                                const float* __restrict__ Wf,
                                                const int* __restrict__ lens, int t,
                                                float* __restrict__ alpha,
                                                float* __restrict__ out_alpha) {
    __shared__ float a2[512], wf[512], es[224], red[256];
    int b = blockIdx.x, tid = threadIdx.x;
    for (int i = tid; i < 512; i += 256) { a2[i] = att2[b * 512 + i]; wf[i] = Wf[i]; }
    __syncthreads();
    int lane = tid & 63, wid = tid >> 6;
    for (int p = wid; p < PP; p += 4) {
        const float* row = att1 + ((size_t)(b * PP + p)) * 512 + lane * 8;
        float4 r0 = *(const float4*)(row);
        float4 r1 = *(const float4*)(row + 4);
        float4 c0 = *(const float4*)(&a2[lane * 8]);
        float4 c1 = *(const float4*)(&a2[lane * 8 + 4]);
        float4 w0 = *(const float4*)(&wf[lane * 8]);
        float4 w1 = *(const float4*)(&wf[lane * 8 + 4]);
        float s = 0.f, v;
        v = r0.x + c0.x; s += (v > 0.f ? v : 0.f) * w0.x;
        v = r0.y + c0.y; s += (v > 0.f ? v : 0.f) * w0.y;
        v = r0.z + c0.z; s += (v > 0.f ? v : 0.f) * w0.z;
        v = r0.w + c0.w; s += (v > 0.f ? v : 0.f) * w0.w;
        v = r1.x + c1.x; s += (v > 0.f ? v : 0.f) * w1.x;
        v = r1.y + c1.y; s += (v > 0.f ? v : 0.f) * w1.y;
        v = r1.z + c1.z; s += (v > 0.f ? v : 0.f) * w1.z;
        v = r1.w + c1.w; s += (v > 0.f ? v : 0.f) * w1.w;
        #pragma unroll
        for (int off = 32; off; off >>= 1) s += __shfl_down(s, off);
        if (lane == 0) es[p] = s;
    }
    __syncthreads();
    float v = (tid < PP) ? es[tid] : -3.4e38f;
    red[tid] = v; __syncthreads();
    for (int s = 128; s; s >>= 1) { if (tid < s) red[tid] = fmaxf(red[tid], red[tid + s]); __syncthreads(); }
    float mx = red[0]; __syncthreads();
    float ev = (tid < PP) ? __expf(v - mx) : 0.f;
    red[tid] = ev; __syncthreads();
    for (int s = 128; s; s >>= 1) { if (tid < s) red[tid] += red[tid + s]; __syncthreads(); }
    float inv = 1.f / red[0];
    if (tid < PP) {
        float al = ev * inv;
        alpha[b * PP + tid] = al;
        bool m = t < (lens[b] - 1);
        out_alpha[((size_t)b * TT + t) * PP + tid] = m ? al : 0.f;
    }
}

// awe[b,e] = gate[b,e] * sum_p alpha[b,p]*enc[b,p,e]
__global__ void k_awe(const float* __restrict__ enc, const float* __restrict__ alpha,
                      const float* __restrict__ gate, float* __restrict__ awe) {
    __shared__ float al[PP];
    int b = blockIdx.y;
    int e = blockIdx.x * 256 + threadIdx.x;
    for (int i = threadIdx.x; i < PP; i += 256) al[i] = alpha[b * PP + i];
    __syncthreads();
    const float* p = enc + (size_t)b * PP * ENCD + e;
    float s = 0.f;
    #pragma unroll 4
    for (int i = 0; i < PP; ++i) s += al[i] * p[(size_t)i * ENCD];
    awe[b * ENCD + e] = s * gate[b * ENCD + e];
}

// K-split partial sums for gates = [x_t, awe]@W_ih + h@W_hh
// kc=0..3: xi chunks of 640; kc=4: h@W_hh
__global__ void k_gpart(const float* __restrict__ Wih, const float* __restrict__ Whh,
                        const float* __restrict__ emb, const int* __restrict__ caps, int t,
                        const float* __restrict__ awe, const float* __restrict__ h,
                        float* __restrict__ part) {
    int idx = blockIdx.x * 256 + threadIdx.x;     // 5*64*512 = 163840
    int kc = idx >> 15;
    int rem = idx & 32767;
    int b = rem >> 9;
    int n4 = (rem & 511) * 4;
    float4 acc = {0.f, 0.f, 0.f, 0.f};
    if (kc < 4) {
        int k0 = kc * 640, k1 = k0 + 640;
        const float* er = emb + (size_t)caps[b * 22 + t] * 512;
        int ke = (k1 < 512) ? k1 : 512;
        for (int k = k0; k < ke; ++k) {
            float x = er[k];
            float4 w = *(const float4*)(Wih + (size_t)k * 2048 + n4);
            acc.x += x * w.x; acc.y += x * w.y; acc.z += x * w.z; acc.w += x * w.w;
        }
        int ks = (k0 > 512) ? k0 : 512;
        const float* ar = awe + (size_t)b * 2048 - 512;
        for (int k = ks; k < k1; ++k) {
            float x = ar[k];
            float4 w = *(const float4*)(Wih + (size_t)k * 2048 + n4);
            acc.x += x * w.x; acc.y += x * w.y; acc.z += x * w.z; acc.w += x * w.w;
        }
    } else {
        const float* hr = h + b * 512;
        for (int d = 0; d < 512; ++d) {
            float x = hr[d];
            float4 w = *(const float4*)(Whh + (size_t)d * 2048 + n4);
            acc.x += x * w.x; acc.y += x * w.y; acc.z += x * w.z; acc.w += x * w.w;
        }
    }
    *(float4*)(part + (size_t)kc * BB * 2048 + (size_t)b * 2048 + n4) = acc;
}

// LSTM pointwise + memory attention + h/c carry (one block per b)
__global__ __launch_bounds__(256) void k_memattn(const float* __restrict__ part,
                                                 const float* __restrict__ bih,
                                                 const float* __restrict__ bhh,
                                                 const int* __restrict__ lens, int t,
                                                 const float* __restrict__ memB,
                                                 float* __restrict__ h, float* __restrict__ c,
                                                 float* __restrict__ hnew) {
    __shared__ float hs[512], sims[128], red[256], ps[128];
    int b = blockIdx.x, tid = threadIdx.x;
    bool msk = t < (lens[b] - 1);
    for (int j = tid; j < 512; j += 256) {
        float g[4];
        #pragma unroll
        for (int q = 0; q < 4; ++q) {
            int col = q * 512 + j;
            float s = bih[col] + bhh[col];
            #pragma unroll
            for (int kc = 0; kc < 5; ++kc) s += part[(size_t)kc * BB * 2048 + (size_t)b * 2048 + col];
            g[q] = s;
        }
        float gi = sigm(g[0]), gf = sigm(g[1]), gg = tanh_f(g[2]), go = sigm(g[3]);
        float cold = c[b * 512 + j];
        float cn = gf * cold + gi * gg;
        c[b * 512 + j] = msk ? cn : cold;
        hs[j] = go * tanh_f(cn);
    }
    __syncthreads();
    int lane = tid & 63, wid = tid >> 6;
    for (int m = wid * 32; m < wid * 32 + 32; ++m) {
        const float* r = memB + (size_t)m * 512 + lane * 8;
        float4 r0 = *(const float4*)(r);
        float4 r1 = *(const float4*)(r + 4);
        float4 h0 = *(const float4*)(&hs[lane * 8]);
        float4 h1 = *(const float4*)(&hs[lane * 8 + 4]);
        float s = r0.x * h0.x + r0.y * h0.y + r0.z * h0.z + r0.w * h0.w
                + r1.x * h1.x + r1.y * h1.y + r1.z * h1.z + r1.w * h1.w;
        #pragma unroll
        for (int off = 32; off; off >>= 1) s += __shfl_down(s, off);
        if (lane == 0) sims[m] = s;
    }
    __syncthreads();
    float v = (tid < 128) ? sims[tid] : -3.4e38f;
    red[tid] = v; __syncthreads();
    for (int s = 128; s; s >>= 1) { if (tid < s) red[tid] = fmaxf(red[tid], red[tid + s]); __syncthreads(); }
    float mx = red[0]; __syncthreads();
    float ev = (tid < 128) ? __expf(v - mx) : 0.f;
    red[tid] = ev; __syncthreads();
    for (int s = 128; s; s >>= 1) { if (tid < s) red[tid] += red[tid + s]; __syncthreads(); }
    if (tid < 128) ps[tid] = ev / red[0];
    __syncthreads();
    for (int d = tid; d < 512; d += 256) {
        float s = 0.f;
        #pragma unroll 4
        for (int m = 0; m < 128; ++m) s += ps[m] * memB[(size_t)m * 512 + d];
        float hn = hs[d] + s;
        hnew[b * 512 + d] = hn;
        float hold = h[b * 512 + d];
        h[b * 512 + d] = msk ? hn : hold;
    }
}

// preds = hnew @ W_fc + b_fc, masked store
__global__ void k_preds(const float* __restrict__ hnew, const float* __restrict__ Wfc,
                        const float* __restrict__ bfc, const int* __restrict__ lens, int t,
                        float* __restrict__ out) {
    int idx = blockIdx.x * 256 + threadIdx.x;     // 64*2500 = 160000
    int b = idx / 2500;
    int v4 = (idx % 2500) * 4;
    const float* hr = hnew + b * 512;
    float4 acc = *(const float4*)(bfc + v4);
    #pragma unroll 4
    for (int d = 0; d < 512; ++d) {
        float x = hr[d];
        float4 w = *(const float4*)(Wfc + (size_t)d * VV + v4);
        acc.x += x * w.x; acc.y += x * w.y; acc.z += x * w.z; acc.w += x * w.w;
    }
    bool m = t < (lens[b] - 1);
    float4 r;
    r.x = m ? acc.x : 0.f; r.y = m ? acc.y : 0.f;
    r.z = m ? acc.z : 0.f; r.w = m ? acc.w : 0.f;
    *(float4*)(out + ((size_t)b * TT + t) * VV + v4) = r;
}

// ---------------- launch ----------------

extern "C" void kernel_launch(void* const* d_in, const int* in_sizes, int n_in,
                              void* d_out, int out_size, void* d_ws, size_t ws_size,
                              hipStream_t stream) {
    const float* enc     = (const float*)d_in[0];
    const int*   caps    = (const int*)d_in[1];
    const int*   lens    = (const int*)d_in[2];
    const float* emb     = (const float*)d_in[3];
    const float* W_enc   = (const float*)d_in[4];
    const float* b_enc   = (const float*)d_in[5];
    const float* W_dec   = (const float*)d_in[6];
    const float* b_dec   = (const float*)d_in[7];
    const float* W_full  = (const float*)d_in[8];
    const float* W_inith = (const float*)d_in[10];
    const float* b_inith = (const float*)d_in[11];
    const float* W_initc = (const float*)d_in[12];
    const float* b_initc = (const float*)d_in[13];
    const float* W_beta  = (const float*)d_in[14];
    const float* b_beta  = (const float*)d_in[15];
    const float* W_ih    = (const float*)d_in[16];
    const float* b_ih    = (const float*)d_in[17];
    const float* W_hh    = (const float*)d_in[18];
    const float* b_hh    = (const float*)d_in[19];
    const float* memB    = (const float*)d_in[20];
    const float* W_fc    = (const float*)d_in[21];
    const float* b_fc    = (const float*)d_in[22];

    float* out = (float*)d_out;
    float* preds_out  = out;
    float* declen_out = out + (size_t)BB * TT * VV;
    float* alpha_out  = declen_out + BB;

    float* ws   = (float*)d_ws;
    float* att1 = ws;  ws += (size_t)12544 * 512;
    float* mean = ws;  ws += BB * ENCD;
    float* h    = ws;  ws += BB * DECD;
    float* c    = ws;  ws += BB * DECD;
    float* att2 = ws;  ws += BB * 512;
    float* gate = ws;  ws += BB * ENCD;
    float* alpha= ws;  ws += BB * PP;
    float* awe  = ws;  ws += BB * ENCD;
    float* hnew = ws;  ws += BB * DECD;
    float* part = ws;  ws += (size_t)5 * BB * 2048;

    k_mean<<<512, 256, 0, stream>>>(enc, mean);
    k_inithc<<<128, 256, 0, stream>>>(mean, W_inith, b_inith, W_initc, b_initc, h, c);
    k_att1<<<dim3(4, 98), 256, 0, stream>>>(enc, W_enc, b_enc, att1);
    k_declen<<<1, 64, 0, stream>>>(lens, declen_out);

    for (int t = 0; t < TT; ++t) {
        k_att2gate<<<640, 256, 0, stream>>>(h, W_dec, b_dec, W_beta, b_beta, att2, gate);
        k_escore<<<64, 256, 0, stream>>>(att1, att2, W_full, lens, t, alpha, alpha_out);
        k_awe<<<dim3(8, 64), 256, 0, stream>>>(enc, alpha, gate, awe);
        k_gpart<<<640, 256, 0, stream>>>(W_ih, W_hh, emb, caps, t, awe, h, part);
        k_memattn<<<64, 256, 0, stream>>>(part, b_ih, b_hh, lens, t, memB, h, c, hnew);
        k_preds<<<625, 256, 0, stream>>>(hnew, W_fc, b_fc, lens, t, preds_out);
    }
}

// Round 2
// 4877.975 us; speedup vs baseline: 1.6273x; 1.6273x over previous
//
#include <hip/hip_runtime.h>

#define BB   64
#define PP   196
#define ENCD 2048
#define DECD 512
#define VV   10000
#define TT   21

typedef __attribute__((ext_vector_type(8))) short bf16x8;
typedef __attribute__((ext_vector_type(4))) float f32x4;

__device__ __forceinline__ float sigm(float x)   { return 1.f / (1.f + __expf(-x)); }
__device__ __forceinline__ float tanh_f(float x) { return 1.f - 2.f / (1.f + __expf(2.f * x)); }
__device__ __forceinline__ ushort f2bf(float x) {
    unsigned u = __float_as_uint(x);
    unsigned r = (u + 0x7FFFu + ((u >> 16) & 1u)) >> 16;
    return (ushort)r;
}

// ---------------- setup kernels ----------------

__global__ void k_mean(const float* __restrict__ enc, float* __restrict__ mean) {
    int idx = blockIdx.x * 256 + threadIdx.x;      // 64*2048
    int b = idx >> 11, e = idx & 2047;
    const float* p = enc + (size_t)b * PP * ENCD + e;
    float s = 0.f;
    #pragma unroll 4
    for (int i = 0; i < PP; ++i) s += p[(size_t)i * ENCD];
    mean[idx] = s * (1.f / 196.f);
}

__global__ void k_inithc(const float* __restrict__ mean,
                         const float* __restrict__ Wh, const float* __restrict__ bh,
                         const float* __restrict__ Wc, const float* __restrict__ bc,
                         float* __restrict__ h, float* __restrict__ c) {
    int idx = blockIdx.x * 256 + threadIdx.x;      // 64*512
    int b = idx >> 9, d = idx & 511;
    const float* m = mean + b * ENCD;
    float ah = 0.f, ac = 0.f;
    #pragma unroll 4
    for (int e = 0; e < ENCD; ++e) {
        float mv = m[e];
        ah += mv * Wh[(size_t)e * DECD + d];
        ac += mv * Wc[(size_t)e * DECD + d];
    }
    h[idx] = ah + bh[d];
    c[idx] = ac + bc[d];
}

// f32->bf16 conversions
__global__ void k_cvt(const float* __restrict__ in, ushort* __restrict__ out, int n4) {
    int i = blockIdx.x * 256 + threadIdx.x;
    if (i >= n4) return;
    float4 v = ((const float4*)in)[i];
    ushort4 o; o.x = f2bf(v.x); o.y = f2bf(v.y); o.z = f2bf(v.z); o.w = f2bf(v.w);
    ((ushort4*)out)[i] = o;
}

// WencT[n][k] = bf16(W_enc[k][n]) : [512][2048]
__global__ void k_cvtT(const float* __restrict__ W, ushort* __restrict__ out) {
    int idx = blockIdx.x * 256 + threadIdx.x;      // 1048576
    int nn = idx >> 11, k = idx & 2047;
    out[idx] = f2bf(W[(size_t)k * 512 + nn]);
}

// att1 = encB @ WencT^T + bias, bf16 MFMA. tile 128x64, 4 waves (2x2), BK=64.
__global__ __launch_bounds__(256) void k_att1_mfma(const ushort* __restrict__ A,
                                                   const ushort* __restrict__ Bt,
                                                   const float* __restrict__ bias,
                                                   float* __restrict__ C) {
    __shared__ alignas(16) ushort As[128 * 64];
    __shared__ alignas(16) ushort Bs[64 * 64];
    const int m0 = blockIdx.y * 128, n0 = blockIdx.x * 64;
    const int tid = threadIdx.x;
    const int wid = tid >> 6, lane = tid & 63;
    const int wr = wid >> 1, wc = wid & 1;
    f32x4 acc[4][2] = {};

    for (int k0 = 0; k0 < 2048; k0 += 64) {
        #pragma unroll
        for (int p = 0; p < 4; ++p) {
            int c = p * 256 + tid;            // 0..1023
            int r = c >> 3, cc = c & 7;
            float4 v = *(const float4*)(A + (size_t)(m0 + r) * 2048 + k0 + cc * 8);
            *(float4*)(As + r * 64 + ((cc ^ (r & 7)) * 8)) = v;
        }
        #pragma unroll
        for (int p = 0; p < 2; ++p) {
            int c = p * 256 + tid;            // 0..511
            int r = c >> 3, cc = c & 7;
            float4 v = *(const float4*)(Bt + (size_t)(n0 + r) * 2048 + k0 + cc * 8);
            *(float4*)(Bs + r * 64 + ((cc ^ (r & 7)) * 8)) = v;
        }
        __syncthreads();
        #pragma unroll
        for (int kk = 0; kk < 2; ++kk) {
            int kg = lane >> 4;
            int ci = kk * 4 + kg;             // 16B-chunk index along K
            bf16x8 bfrag[2];
            #pragma unroll
            for (int n = 0; n < 2; ++n) {
                int col = wc * 32 + n * 16 + (lane & 15);
                bfrag[n] = *(const bf16x8*)(Bs + col * 64 + ((ci ^ (col & 7)) * 8));
            }
            #pragma unroll
            for (int m = 0; m < 4; ++m) {
                int row = wr * 64 + m * 16 + (lane & 15);
                bf16x8 afrag = *(const bf16x8*)(As + row * 64 + ((ci ^ (row & 7)) * 8));
                #pragma unroll
                for (int n = 0; n < 2; ++n)
                    acc[m][n] = __builtin_amdgcn_mfma_f32_16x16x32_bf16(afrag, bfrag[n], acc[m][n], 0, 0, 0);
            }
        }
        __syncthreads();
    }
    #pragma unroll
    for (int m = 0; m < 4; ++m) {
        int row_base = m0 + wr * 64 + m * 16 + (lane >> 4) * 4;
        #pragma unroll
        for (int n = 0; n < 2; ++n) {
            int col = n0 + wc * 32 + n * 16 + (lane & 15);
            float bv = bias[col];
            #pragma unroll
            for (int r = 0; r < 4; ++r)
                C[(size_t)(row_base + r) * 512 + col] = acc[m][n][r] + bv;
        }
    }
}

// f32 fallback att1 (used only if ws too small for bf16 path)
__global__ __launch_bounds__(256) void k_att1(const float* __restrict__ A,
                                              const float* __restrict__ W,
                                              const float* __restrict__ bias,
                                              float* __restrict__ C) {
    __shared__ float As[16][128];
    __shared__ float Bs[16][128];
    const int m0 = blockIdx.y * 128;
    const int n0 = blockIdx.x * 128;
    const int tid = threadIdx.x;
    const int tx = tid & 15, ty = tid >> 4;
    float acc[8][8] = {};
    const int am = tid >> 2;
    const int ak = (tid & 3) * 4;
    const int bk = tid >> 5;
    const int bn = (tid & 31) * 4;
    for (int k0 = 0; k0 < 2048; k0 += 16) {
        #pragma unroll
        for (int pass = 0; pass < 2; ++pass) {
            int m = am + pass * 64;
            float4 v = *(const float4*)(A + (size_t)(m0 + m) * 2048 + k0 + ak);
            As[ak + 0][m] = v.x; As[ak + 1][m] = v.y;
            As[ak + 2][m] = v.z; As[ak + 3][m] = v.w;
        }
        #pragma unroll
        for (int pass = 0; pass < 2; ++pass) {
            int k = bk + pass * 8;
            float4 v = *(const float4*)(W + (size_t)(k0 + k) * 512 + n0 + bn);
            *(float4*)&Bs[k][bn] = v;
        }
        __syncthreads();
        #pragma unroll
        for (int kk = 0; kk < 16; ++kk) {
            float4 a0 = *(const float4*)&As[kk][ty * 8];
            float4 a1 = *(const float4*)&As[kk][ty * 8 + 4];
            float4 b0 = *(const float4*)&Bs[kk][tx * 8];
            float4 b1 = *(const float4*)&Bs[kk][tx * 8 + 4];
            float av[8] = {a0.x, a0.y, a0.z, a0.w, a1.x, a1.y, a1.z, a1.w};
            float bv[8] = {b0.x, b0.y, b0.z, b0.w, b1.x, b1.y, b1.z, b1.w};
            #pragma unroll
            for (int i = 0; i < 8; ++i)
                #pragma unroll
                for (int j = 0; j < 8; ++j) acc[i][j] += av[i] * bv[j];
        }
        __syncthreads();
    }
    #pragma unroll
    for (int i = 0; i < 8; ++i) {
        int row = m0 + ty * 8 + i;
        #pragma unroll
        for (int j = 0; j < 8; ++j) {
            int col = n0 + tx * 8 + j;
            C[(size_t)row * 512 + col] = acc[i][j] + bias[col];
        }
    }
}

__global__ void k_declen(const int* __restrict__ lens, float* __restrict__ out) {
    int b = threadIdx.x;
    if (b < BB) out[b] = (float)(lens[b] - 1);
}

// ---------------- per-step kernels ----------------

// C[64 x 2560] = h @ [W_dec | W_beta], tiled 64x64, K=512
__global__ __launch_bounds__(256) void k_att2gate(const float* __restrict__ h,
                           const float* __restrict__ Wd, const float* __restrict__ bd,
                           const float* __restrict__ Wb, const float* __restrict__ bb,
                           float* __restrict__ att2, float* __restrict__ gate) {
    __shared__ alignas(16) float As[32][68];   // [k][m]
    __shared__ alignas(16) float Bs[32][68];   // [k][n]
    const int n0 = blockIdx.x * 64;
    const bool isg = n0 >= 512;
    const float* Bp = isg ? Wb : Wd;
    const int bstride = isg ? 2048 : 512;
    const int coff = isg ? n0 - 512 : n0;
    const int tid = threadIdx.x, tx = tid & 15, ty = tid >> 4;
    float acc[4][4] = {};
    for (int k0 = 0; k0 < 512; k0 += 32) {
        #pragma unroll
        for (int p = 0; p < 2; ++p) {
            int c = p * 256 + tid;
            int m = c >> 3, k4 = (c & 7) * 4;
            float4 v = *(const float4*)(h + m * 512 + k0 + k4);
            As[k4 + 0][m] = v.x; As[k4 + 1][m] = v.y; As[k4 + 2][m] = v.z; As[k4 + 3][m] = v.w;
            int kb = c >> 4, n4 = (c & 15) * 4;
            float4 w = *(const float4*)(Bp + (size_t)(k0 + kb) * bstride + coff + n4);
            *(float4*)&Bs[kb][n4] = w;
        }
        __syncthreads();
        #pragma unroll 8
        for (int k = 0; k < 32; ++k) {
            float4 a = *(const float4*)&As[k][ty * 4];
            float4 b = *(const float4*)&Bs[k][tx * 4];
            float av[4] = {a.x, a.y, a.z, a.w}, bv[4] = {b.x, b.y, b.z, b.w};
            #pragma unroll
            for (int i = 0; i < 4; ++i)
                #pragma unroll
                for (int j = 0; j < 4; ++j) acc[i][j] += av[i] * bv[j];
        }
        __syncthreads();
    }
    #pragma unroll
    for (int i = 0; i < 4; ++i) {
        int m = ty * 4 + i;
        #pragma unroll
        for (int j = 0; j < 4; ++j) {
            int n = n0 + tx * 4 + j;
            if (isg) gate[m * 2048 + (n - 512)] = sigm(acc[i][j] + bb[n - 512]);
            else     att2[m * 512 + n] = acc[i][j] + bd[n];
        }
    }
}

// e scores + softmax -> alpha (one block per b)
__global__ __launch_bounds__(256) void k_escore(const float* __restrict__ att1,
                                                const float* __restrict__ att2,
                                                const float* __restrict__ Wf,
                                                const int* __restrict__ lens, int t,
                                                float* __restrict__ alpha,
                                                float* __restrict__ out_alpha) {
    __shared__ float a2[512], wf[512], es[224], red[256];
    int b = blockIdx.x, tid = threadIdx.x;
    for (int i = tid; i < 512; i += 256) { a2[i] = att2[b * 512 + i]; wf[i] = Wf[i]; }
    __syncthreads();
    int lane = tid & 63, wid = tid >> 6;
    for (int p = wid; p < PP; p += 4) {
        const float* row = att1 + ((size_t)(b * PP + p)) * 512 + lane * 8;
        float4 r0 = *(const float4*)(row);
        float4 r1 = *(const float4*)(row + 4);
        float4 c0 = *(const float4*)(&a2[lane * 8]);
        float4 c1 = *(const float4*)(&a2[lane * 8 + 4]);
        float4 w0 = *(const float4*)(&wf[lane * 8]);
        float4 w1 = *(const float4*)(&wf[lane * 8 + 4]);
        float s = 0.f, v;
        v = r0.x + c0.x; s += (v > 0.f ? v : 0.f) * w0.x;
        v = r0.y + c0.y; s += (v > 0.f ? v : 0.f) * w0.y;
        v = r0.z + c0.z; s += (v > 0.f ? v : 0.f) * w0.z;
        v = r0.w + c0.w; s += (v > 0.f ? v : 0.f) * w0.w;
        v = r1.x + c1.x; s += (v > 0.f ? v : 0.f) * w1.x;
        v = r1.y + c1.y; s += (v > 0.f ? v : 0.f) * w1.y;
        v = r1.z + c1.z; s += (v > 0.f ? v : 0.f) * w1.z;
        v = r1.w + c1.w; s += (v > 0.f ? v : 0.f) * w1.w;
        #pragma unroll
        for (int off = 32; off; off >>= 1) s += __shfl_down(s, off);
        if (lane == 0) es[p] = s;
    }
    __syncthreads();
    float v = (tid < PP) ? es[tid] : -3.4e38f;
    red[tid] = v; __syncthreads();
    for (int s = 128; s; s >>= 1) { if (tid < s) red[tid] = fmaxf(red[tid], red[tid + s]); __syncthreads(); }
    float mx = red[0]; __syncthreads();
    float ev = (tid < PP) ? __expf(v - mx) : 0.f;
    red[tid] = ev; __syncthreads();
    for (int s = 128; s; s >>= 1) { if (tid < s) red[tid] += red[tid + s]; __syncthreads(); }
    float inv = 1.f / red[0];
    if (tid < PP) {
        float al = ev * inv;
        alpha[b * PP + tid] = al;
        bool m = t < (lens[b] - 1);
        out_alpha[((size_t)b * TT + t) * PP + tid] = m ? al : 0.f;
    }
}

// awe[b,e] = gate[b,e] * sum_p alpha[b,p]*enc[b,p,e]
__global__ void k_awe(const float* __restrict__ enc, const float* __restrict__ alpha,
                      const float* __restrict__ gate, float* __restrict__ awe) {
    __shared__ float al[PP];
    int b = blockIdx.y;
    int e = blockIdx.x * 256 + threadIdx.x;
    for (int i = threadIdx.x; i < PP; i += 256) al[i] = alpha[b * PP + i];
    __syncthreads();
    const float* p = enc + (size_t)b * PP * ENCD + e;
    float s = 0.f;
    #pragma unroll 4
    for (int i = 0; i < PP; ++i) s += al[i] * p[(size_t)i * ENCD];
    awe[b * ENCD + e] = s * gate[b * ENCD + e];
}

// gates partials: K split into 6 chunks of 512 (emb | 4x awe | h), tile 64x64
__global__ __launch_bounds__(256) void k_gates_part(const float* __restrict__ Wih,
                        const float* __restrict__ Whh,
                        const float* __restrict__ emb, const int* __restrict__ caps, int t,
                        const float* __restrict__ awe, const float* __restrict__ h,
                        float* __restrict__ part) {
    __shared__ alignas(16) float As[32][68];
    __shared__ alignas(16) float Bs[32][68];
    const int n0 = blockIdx.x * 64;
    const int kc = blockIdx.y;                 // 0..5
    const float* Bp = (kc < 5) ? (Wih + (size_t)kc * 512 * 2048) : Whh;
    const int tid = threadIdx.x, tx = tid & 15, ty = tid >> 4;
    float acc[4][4] = {};
    for (int k0 = 0; k0 < 512; k0 += 32) {
        #pragma unroll
        for (int p = 0; p < 2; ++p) {
            int c = p * 256 + tid;
            int m = c >> 3, k4 = (c & 7) * 4;
            const float* ap;
            if (kc == 0)     ap = emb + (size_t)caps[m * 22 + t] * 512 + k0 + k4;
            else if (kc < 5) ap = awe + m * 2048 + (kc - 1) * 512 + k0 + k4;
            else             ap = h + m * 512 + k0 + k4;
            float4 v = *(const float4*)ap;
            As[k4 + 0][m] = v.x; As[k4 + 1][m] = v.y; As[k4 + 2][m] = v.z; As[k4 + 3][m] = v.w;
            int kb = c >> 4, n4 = (c & 15) * 4;
            float4 w = *(const float4*)(Bp + (size_t)(k0 + kb) * 2048 + n0 + n4);
            *(float4*)&Bs[kb][n4] = w;
        }
        __syncthreads();
        #pragma unroll 8
        for (int k = 0; k < 32; ++k) {
            float4 a = *(const float4*)&As[k][ty * 4];
            float4 b = *(const float4*)&Bs[k][tx * 4];
            float av[4] = {a.x, a.y, a.z, a.w}, bv[4] = {b.x, b.y, b.z, b.w};
            #pragma unroll
            for (int i = 0; i < 4; ++i)
                #pragma unroll
                for (int j = 0; j < 4; ++j) acc[i][j] += av[i] * bv[j];
        }
        __syncthreads();
    }
    #pragma unroll
    for (int i = 0; i < 4; ++i) {
        int m = ty * 4 + i;
        #pragma unroll
        for (int j = 0; j < 4; ++j) {
            int n = n0 + tx * 4 + j;
            part[((size_t)kc * BB + m) * 2048 + n] = acc[i][j];
        }
    }
}

// LSTM pointwise + memory attention + h/c carry (one block per b)
__global__ __launch_bounds__(256) void k_memattn(const float* __restrict__ part,
                                                 const float* __restrict__ bih,
                                                 const float* __restrict__ bhh,
                                                 const int* __restrict__ lens, int t,
                                                 const float* __restrict__ memB,
                                                 float* __restrict__ h, float* __restrict__ c,
                                                 float* __restrict__ hnew) {
    __shared__ float hs[512], sims[128], red[256], ps[128];
    int b = blockIdx.x, tid = threadIdx.x;
    bool msk = t < (lens[b] - 1);
    for (int j = tid; j < 512; j += 256) {
        float g[4];
        #pragma unroll
        for (int q = 0; q < 4; ++q) {
            int col = q * 512 + j;
            float s = bih[col] + bhh[col];
            #pragma unroll
            for (int kc = 0; kc < 6; ++kc) s += part[((size_t)kc * BB + b) * 2048 + col];
            g[q] = s;
        }
        float gi = sigm(g[0]), gf = sigm(g[1]), gg = tanh_f(g[2]), go = sigm(g[3]);
        float cold = c[b * 512 + j];
        float cn = gf * cold + gi * gg;
        c[b * 512 + j] = msk ? cn : cold;
        hs[j] = go * tanh_f(cn);
    }
    __syncthreads();
    int lane = tid & 63, wid = tid >> 6;
    for (int m = wid * 32; m < wid * 32 + 32; ++m) {
        const float* r = memB + (size_t)m * 512 + lane * 8;
        float4 r0 = *(const float4*)(r);
        float4 r1 = *(const float4*)(r + 4);
        float4 h0 = *(const float4*)(&hs[lane * 8]);
        float4 h1 = *(const float4*)(&hs[lane * 8 + 4]);
        float s = r0.x * h0.x + r0.y * h0.y + r0.z * h0.z + r0.w * h0.w
                + r1.x * h1.x + r1.y * h1.y + r1.z * h1.z + r1.w * h1.w;
        #pragma unroll
        for (int off = 32; off; off >>= 1) s += __shfl_down(s, off);
        if (lane == 0) sims[m] = s;
    }
    __syncthreads();
    float v = (tid < 128) ? sims[tid] : -3.4e38f;
    red[tid] = v; __syncthreads();
    for (int s = 128; s; s >>= 1) { if (tid < s) red[tid] = fmaxf(red[tid], red[tid + s]); __syncthreads(); }
    float mx = red[0]; __syncthreads();
    float ev = (tid < 128) ? __expf(v - mx) : 0.f;
    red[tid] = ev; __syncthreads();
    for (int s = 128; s; s >>= 1) { if (tid < s) red[tid] += red[tid + s]; __syncthreads(); }
    if (tid < 128) ps[tid] = ev / red[0];
    __syncthreads();
    for (int d = tid; d < 512; d += 256) {
        float s = 0.f;
        #pragma unroll 4
        for (int m = 0; m < 128; ++m) s += ps[m] * memB[(size_t)m * 512 + d];
        float hn = hs[d] + s;
        hnew[b * 512 + d] = hn;
        float hold = h[b * 512 + d];
        h[b * 512 + d] = msk ? hn : hold;
    }
}

// preds = hnew @ W_fc + b_fc, tile 64x64, K=512, masked store
__global__ __launch_bounds__(256) void k_preds(const float* __restrict__ hnew,
                        const float* __restrict__ Wfc,
                        const float* __restrict__ bfc, const int* __restrict__ lens, int t,
                        float* __restrict__ out) {
    __shared__ alignas(16) float As[32][68];
    __shared__ alignas(16) float Bs[32][68];
    const int n0 = blockIdx.x * 64;
    const int tid = threadIdx.x, tx = tid & 15, ty = tid >> 4;
    float acc[4][4] = {};
    for (int k0 = 0; k0 < 512; k0 += 32) {
        #pragma unroll
        for (int p = 0; p < 2; ++p) {
            int c = p * 256 + tid;
            int m = c >> 3, k4 = (c & 7) * 4;
            float4 v = *(const float4*)(hnew + m * 512 + k0 + k4);
            As[k4 + 0][m] = v.x; As[k4 + 1][m] = v.y; As[k4 + 2][m] = v.z; As[k4 + 3][m] = v.w;
            int kb = c >> 4, n4 = (c & 15) * 4;
            int n = n0 + n4;
            float4 w = {0.f, 0.f, 0.f, 0.f};
            if (n < VV) w = *(const float4*)(Wfc + (size_t)(k0 + kb) * VV + n);
            *(float4*)&Bs[kb][n4] = w;
        }
        __syncthreads();
        #pragma unroll 8
        for (int k = 0; k < 32; ++k) {
            float4 a = *(const float4*)&As[k][ty * 4];
            float4 b = *(const float4*)&Bs[k][tx * 4];
            float av[4] = {a.x, a.y, a.z, a.w}, bv[4] = {b.x, b.y, b.z, b.w};
            #pragma unroll
            for (int i = 0; i < 4; ++i)
                #pragma unroll
                for (int j = 0; j < 4; ++j) acc[i][j] += av[i] * bv[j];
        }
        __syncthreads();
    }
    #pragma unroll
    for (int i = 0; i < 4; ++i) {
        int m = ty * 4 + i;
        bool msk = t < (lens[m] - 1);
        #pragma unroll
        for (int j = 0; j < 4; ++j) {
            int n = n0 + tx * 4 + j;
            if (n < VV) {
                float vv = msk ? (acc[i][j] + bfc[n]) : 0.f;
                out[((size_t)m * TT + t) * VV + n] = vv;
            }
        }
    }
}

// ---------------- launch ----------------

extern "C" void kernel_launch(void* const* d_in, const int* in_sizes, int n_in,
                              void* d_out, int out_size, void* d_ws, size_t ws_size,
                              hipStream_t stream) {
    const float* enc     = (const float*)d_in[0];
    const int*   caps    = (const int*)d_in[1];
    const int*   lens    = (const int*)d_in[2];
    const float* emb     = (const float*)d_in[3];
    const float* W_enc   = (const float*)d_in[4];
    const float* b_enc   = (const float*)d_in[5];
    const float* W_dec   = (const float*)d_in[6];
    const float* b_dec   = (const float*)d_in[7];
    const float* W_full  = (const float*)d_in[8];
    const float* W_inith = (const float*)d_in[10];
    const float* b_inith = (const float*)d_in[11];
    const float* W_initc = (const float*)d_in[12];
    const float* b_initc = (const float*)d_in[13];
    const float* W_beta  = (const float*)d_in[14];
    const float* b_beta  = (const float*)d_in[15];
    const float* W_ih    = (const float*)d_in[16];
    const float* b_ih    = (const float*)d_in[17];
    const float* W_hh    = (const float*)d_in[18];
    const float* b_hh    = (const float*)d_in[19];
    const float* memB    = (const float*)d_in[20];
    const float* W_fc    = (const float*)d_in[21];
    const float* b_fc    = (const float*)d_in[22];

    float* out = (float*)d_out;
    float* preds_out  = out;
    float* declen_out = out + (size_t)BB * TT * VV;
    float* alpha_out  = declen_out + BB;

    float* ws   = (float*)d_ws;
    float* att1 = ws;  ws += (size_t)12544 * 512;
    float* mean = ws;  ws += BB * ENCD;
    float* h    = ws;  ws += BB * DECD;
    float* c    = ws;  ws += BB * DECD;
    float* att2 = ws;  ws += BB * 512;
    float* gate = ws;  ws += BB * ENCD;
    float* alpha= ws;  ws += BB * PP;
    float* awe  = ws;  ws += BB * ENCD;
    float* hnew = ws;  ws += BB * DECD;
    float* part = ws;  ws += (size_t)6 * BB * 2048;
    ushort* encB  = (ushort*)ws;
    ushort* WencT = encB + (size_t)12544 * 2048;

    size_t need = ((char*)(WencT + (size_t)512 * 2048)) - ((char*)d_ws);
    bool use_mfma = ws_size >= need;

    k_mean<<<512, 256, 0, stream>>>(enc, mean);
    k_inithc<<<128, 256, 0, stream>>>(mean, W_inith, b_inith, W_initc, b_initc, h, c);
    if (use_mfma) {
        k_cvt<<<(12544 * 2048 / 4 + 255) / 256, 256, 0, stream>>>(enc, encB, 12544 * 2048 / 4);
        k_cvtT<<<(512 * 2048) / 256, 256, 0, stream>>>(W_enc, WencT);
        k_att1_mfma<<<dim3(8, 98), 256, 0, stream>>>(encB, WencT, b_enc, att1);
    } else {
        k_att1<<<dim3(4, 98), 256, 0, stream>>>(enc, W_enc, b_enc, att1);
    }
    k_declen<<<1, 64, 0, stream>>>(lens, declen_out);

    for (int t = 0; t < TT; ++t) {
        k_att2gate<<<40, 256, 0, stream>>>(h, W_dec, b_dec, W_beta, b_beta, att2, gate);
        k_escore<<<64, 256, 0, stream>>>(att1, att2, W_full, lens, t, alpha, alpha_out);
        k_awe<<<dim3(8, 64), 256, 0, stream>>>(enc, alpha, gate, awe);
        k_gates_part<<<dim3(32, 6), 256, 0, stream>>>(W_ih, W_hh, emb, caps, t, awe, h, part);
        k_memattn<<<64, 256, 0, stream>>>(part, b_ih, b_hh, lens, t, memB, h, c, hnew);
        k_preds<<<157, 256, 0, stream>>>(hnew, W_fc, b_fc, lens, t, preds_out);
    }
}

// Round 3
// 3954.370 us; speedup vs baseline: 2.0074x; 1.2336x over previous
//
#include <hip/hip_runtime.h>

#define BB   64
#define PP   196
#define ENCD 2048
#define DECD 512
#define VV   10000
#define TT   21

typedef __attribute__((ext_vector_type(8))) short bf16x8;
typedef __attribute__((ext_vector_type(4))) float f32x4;

__device__ __forceinline__ float sigm(float x)   { return 1.f / (1.f + __expf(-x)); }
__device__ __forceinline__ float tanh_f(float x) { return 1.f - 2.f / (1.f + __expf(2.f * x)); }
__device__ __forceinline__ ushort f2bf(float x) {
    unsigned u = __float_as_uint(x);
    unsigned r = (u + 0x7FFFu + ((u >> 16) & 1u)) >> 16;
    return (ushort)r;
}

// ---------------- setup kernels ----------------

__global__ void k_mean(const float* __restrict__ enc, float* __restrict__ mean) {
    int idx = blockIdx.x * 256 + threadIdx.x;      // 64*2048
    int b = idx >> 11, e = idx & 2047;
    const float* p = enc + (size_t)b * PP * ENCD + e;
    float s = 0.f;
    #pragma unroll 4
    for (int i = 0; i < PP; ++i) s += p[(size_t)i * ENCD];
    mean[idx] = s * (1.f / 196.f);
}

// h0/c0 partial GEMM: grid (8 ntiles, 4 kc, 2 mat), tile 64x64, K-chunk 512
__global__ __launch_bounds__(256) void k_ipart(const float* __restrict__ mean,
        const float* __restrict__ Wh, const float* __restrict__ Wc,
        float* __restrict__ ipart) {
    __shared__ alignas(16) float As[32][68];
    __shared__ alignas(16) float Bs[32][68];
    const int n0 = blockIdx.x * 64;
    const int kc = blockIdx.y;
    const int mat = blockIdx.z;
    const float* Bp = mat ? Wc : Wh;
    const int tid = threadIdx.x, tx = tid & 15, ty = tid >> 4;
    float acc[4][4] = {};
    for (int k0 = 0; k0 < 512; k0 += 32) {
        #pragma unroll
        for (int p = 0; p < 2; ++p) {
            int c = p * 256 + tid;
            int m = c >> 3, k4 = (c & 7) * 4;
            float4 v = *(const float4*)(mean + m * 2048 + kc * 512 + k0 + k4);
            As[k4 + 0][m] = v.x; As[k4 + 1][m] = v.y; As[k4 + 2][m] = v.z; As[k4 + 3][m] = v.w;
            int kb = c >> 4, n4 = (c & 15) * 4;
            float4 w = *(const float4*)(Bp + (size_t)(kc * 512 + k0 + kb) * 512 + n0 + n4);
            *(float4*)&Bs[kb][n4] = w;
        }
        __syncthreads();
        #pragma unroll 8
        for (int k = 0; k < 32; ++k) {
            float4 a = *(const float4*)&As[k][ty * 4];
            float4 b = *(const float4*)&Bs[k][tx * 4];
            float av[4] = {a.x, a.y, a.z, a.w}, bv[4] = {b.x, b.y, b.z, b.w};
            #pragma unroll
            for (int i = 0; i < 4; ++i)
                #pragma unroll
                for (int j = 0; j < 4; ++j) acc[i][j] += av[i] * bv[j];
        }
        __syncthreads();
    }
    #pragma unroll
    for (int i = 0; i < 4; ++i) {
        int m = ty * 4 + i;
        #pragma unroll
        for (int j = 0; j < 4; ++j) {
            int n = n0 + tx * 4 + j;
            ipart[((size_t)(mat * 4 + kc) * BB + m) * 512 + n] = acc[i][j];
        }
    }
}

__global__ void k_ifin(const float* __restrict__ ipart,
                       const float* __restrict__ bh, const float* __restrict__ bc,
                       float* __restrict__ h, float* __restrict__ c) {
    int idx = blockIdx.x * 256 + threadIdx.x;     // 2*64*512
    int mat = idx >> 15, rem = idx & 32767;
    int b = rem >> 9, d = rem & 511;
    float s = 0.f;
    #pragma unroll
    for (int kc = 0; kc < 4; ++kc) s += ipart[((size_t)(mat * 4 + kc) * BB + b) * 512 + d];
    if (mat) c[rem] = s + bc[d];
    else     h[rem] = s + bh[d];
}

// f32->bf16 elementwise
__global__ void k_cvt(const float* __restrict__ in, ushort* __restrict__ out, int n4) {
    int i = blockIdx.x * 256 + threadIdx.x;
    if (i >= n4) return;
    float4 v = ((const float4*)in)[i];
    ushort4 o; o.x = f2bf(v.x); o.y = f2bf(v.y); o.z = f2bf(v.z); o.w = f2bf(v.w);
    ((ushort4*)out)[i] = o;
}

// transpose+convert: in[K][N] f32 -> out[Npad][K] bf16 (zero-pad n>=N)
__global__ __launch_bounds__(256) void k_tcvt(const float* __restrict__ in,
        ushort* __restrict__ out, int K, int N) {
    __shared__ float lds[64 * 65];
    const int k0 = blockIdx.x * 64, n0 = blockIdx.y * 64;
    const int tid = threadIdx.x;
    for (int i = tid; i < 4096; i += 256) {
        int kk = i >> 6, nn = i & 63;
        float v = 0.f;
        if (n0 + nn < N) v = in[(size_t)(k0 + kk) * N + n0 + nn];
        lds[nn * 65 + kk] = v;
    }
    __syncthreads();
    for (int i = tid; i < 4096; i += 256) {
        int nn = i >> 6, kk = i & 63;
        out[(size_t)(n0 + nn) * K + k0 + kk] = f2bf(lds[nn * 65 + kk]);
    }
}

// att1 = encB @ WencT^T + bias, bf16 MFMA. tile 128x64, 4 waves (2x2), BK=64.
__global__ __launch_bounds__(256) void k_att1_mfma(const ushort* __restrict__ A,
                                                   const ushort* __restrict__ Bt,
                                                   const float* __restrict__ bias,
                                                   float* __restrict__ C) {
    __shared__ alignas(16) ushort As[128 * 64];
    __shared__ alignas(16) ushort Bs[64 * 64];
    const int m0 = blockIdx.y * 128, n0 = blockIdx.x * 64;
    const int tid = threadIdx.x;
    const int wid = tid >> 6, lane = tid & 63;
    const int wr = wid >> 1, wc = wid & 1;
    f32x4 acc[4][2] = {};

    for (int k0 = 0; k0 < 2048; k0 += 64) {
        #pragma unroll
        for (int p = 0; p < 4; ++p) {
            int c = p * 256 + tid;
            int r = c >> 3, cc = c & 7;
            float4 v = *(const float4*)(A + (size_t)(m0 + r) * 2048 + k0 + cc * 8);
            *(float4*)(As + r * 64 + ((cc ^ (r & 7)) * 8)) = v;
        }
        #pragma unroll
        for (int p = 0; p < 2; ++p) {
            int c = p * 256 + tid;
            int r = c >> 3, cc = c & 7;
            float4 v = *(const float4*)(Bt + (size_t)(n0 + r) * 2048 + k0 + cc * 8);
            *(float4*)(Bs + r * 64 + ((cc ^ (r & 7)) * 8)) = v;
        }
        __syncthreads();
        #pragma unroll
        for (int kk = 0; kk < 2; ++kk) {
            int ci = kk * 4 + (lane >> 4);
            bf16x8 bfrag[2];
            #pragma unroll
            for (int n = 0; n < 2; ++n) {
                int col = wc * 32 + n * 16 + (lane & 15);
                bfrag[n] = *(const bf16x8*)(Bs + col * 64 + ((ci ^ (col & 7)) * 8));
            }
            #pragma unroll
            for (int m = 0; m < 4; ++m) {
                int row = wr * 64 + m * 16 + (lane & 15);
                bf16x8 afrag = *(const bf16x8*)(As + row * 64 + ((ci ^ (row & 7)) * 8));
                #pragma unroll
                for (int n = 0; n < 2; ++n)
                    acc[m][n] = __builtin_amdgcn_mfma_f32_16x16x32_bf16(afrag, bfrag[n], acc[m][n], 0, 0, 0);
            }
        }
        __syncthreads();
    }
    #pragma unroll
    for (int m = 0; m < 4; ++m) {
        int row_base = m0 + wr * 64 + m * 16 + (lane >> 4) * 4;
        #pragma unroll
        for (int n = 0; n < 2; ++n) {
            int col = n0 + wc * 32 + n * 16 + (lane & 15);
            float bv = bias[col];
            #pragma unroll
            for (int r = 0; r < 4; ++r)
                C[(size_t)(row_base + r) * 512 + col] = acc[m][n][r] + bv;
        }
    }
}

// f32 fallback att1
__global__ __launch_bounds__(256) void k_att1(const float* __restrict__ A,
                                              const float* __restrict__ W,
                                              const float* __restrict__ bias,
                                              float* __restrict__ C) {
    __shared__ float As[16][128];
    __shared__ float Bs[16][128];
    const int m0 = blockIdx.y * 128;
    const int n0 = blockIdx.x * 128;
    const int tid = threadIdx.x;
    const int tx = tid & 15, ty = tid >> 4;
    float acc[8][8] = {};
    const int am = tid >> 2;
    const int ak = (tid & 3) * 4;
    const int bk = tid >> 5;
    const int bn = (tid & 31) * 4;
    for (int k0 = 0; k0 < 2048; k0 += 16) {
        #pragma unroll
        for (int pass = 0; pass < 2; ++pass) {
            int m = am + pass * 64;
            float4 v = *(const float4*)(A + (size_t)(m0 + m) * 2048 + k0 + ak);
            As[ak + 0][m] = v.x; As[ak + 1][m] = v.y;
            As[ak + 2][m] = v.z; As[ak + 3][m] = v.w;
        }
        #pragma unroll
        for (int pass = 0; pass < 2; ++pass) {
            int k = bk + pass * 8;
            float4 v = *(const float4*)(W + (size_t)(k0 + k) * 512 + n0 + bn);
            *(float4*)&Bs[k][bn] = v;
        }
        __syncthreads();
        #pragma unroll
        for (int kk = 0; kk < 16; ++kk) {
            float4 a0 = *(const float4*)&As[kk][ty * 8];
            float4 a1 = *(const float4*)&As[kk][ty * 8 + 4];
            float4 b0 = *(const float4*)&Bs[kk][tx * 8];
            float4 b1 = *(const float4*)&Bs[kk][tx * 8 + 4];
            float av[8] = {a0.x, a0.y, a0.z, a0.w, a1.x, a1.y, a1.z, a1.w};
            float bv[8] = {b0.x, b0.y, b0.z, b0.w, b1.x, b1.y, b1.z, b1.w};
            #pragma unroll
            for (int i = 0; i < 8; ++i)
                #pragma unroll
                for (int j = 0; j < 8; ++j) acc[i][j] += av[i] * bv[j];
        }
        __syncthreads();
    }
    #pragma unroll
    for (int i = 0; i < 8; ++i) {
        int row = m0 + ty * 8 + i;
        #pragma unroll
        for (int j = 0; j < 8; ++j) {
            int col = n0 + tx * 8 + j;
            C[(size_t)row * 512 + col] = acc[i][j] + bias[col];
        }
    }
}

__global__ void k_declen(const int* __restrict__ lens, float* __restrict__ out) {
    int b = threadIdx.x;
    if (b < BB) out[b] = (float)(lens[b] - 1);
}

// ---------------- per-step kernels ----------------

// P1: all h/emb-dependent GEMMs in one launch. 104 blocks, tile 64x64, K=512.
// seg0 (0..7):   att2 = h@W_dec + b_dec
// seg1 (8..39):  gate = sigm(h@W_beta + b_beta)
// seg2 (40..71): part[5] = h@W_hh
// seg3 (72..103):part[0] = emb_t@W_ih[0:512]
__global__ __launch_bounds__(256) void k_hgemm(const float* __restrict__ h,
        const float* __restrict__ emb, const int* __restrict__ caps, int t,
        const float* __restrict__ Wd, const float* __restrict__ bd,
        const float* __restrict__ Wb, const float* __restrict__ bb,
        const float* __restrict__ Whh, const float* __restrict__ Wih,
        float* __restrict__ att2, float* __restrict__ gate, float* __restrict__ part) {
    __shared__ alignas(16) float As[32][68];
    __shared__ alignas(16) float Bs[32][68];
    const int bx = blockIdx.x;
    int seg, n0, bstride;
    const float* Bp;
    if (bx < 8)       { seg = 0; n0 = bx * 64;        Bp = Wd;  bstride = 512; }
    else if (bx < 40) { seg = 1; n0 = (bx - 8) * 64;  Bp = Wb;  bstride = 2048; }
    else if (bx < 72) { seg = 2; n0 = (bx - 40) * 64; Bp = Whh; bstride = 2048; }
    else              { seg = 3; n0 = (bx - 72) * 64; Bp = Wih; bstride = 2048; }
    const int tid = threadIdx.x, tx = tid & 15, ty = tid >> 4;
    float acc[4][4] = {};
    for (int k0 = 0; k0 < 512; k0 += 32) {
        #pragma unroll
        for (int p = 0; p < 2; ++p) {
            int c = p * 256 + tid;
            int m = c >> 3, k4 = (c & 7) * 4;
            const float* ap = (seg == 3) ? (emb + (size_t)caps[m * 22 + t] * 512 + k0 + k4)
                                         : (h + m * 512 + k0 + k4);
            float4 v = *(const float4*)ap;
            As[k4 + 0][m] = v.x; As[k4 + 1][m] = v.y; As[k4 + 2][m] = v.z; As[k4 + 3][m] = v.w;
            int kb = c >> 4, n4 = (c & 15) * 4;
            float4 w = *(const float4*)(Bp + (size_t)(k0 + kb) * bstride + n0 + n4);
            *(float4*)&Bs[kb][n4] = w;
        }
        __syncthreads();
        #pragma unroll 8
        for (int k = 0; k < 32; ++k) {
            float4 a = *(const float4*)&As[k][ty * 4];
            float4 b = *(const float4*)&Bs[k][tx * 4];
            float av[4] = {a.x, a.y, a.z, a.w}, bv[4] = {b.x, b.y, b.z, b.w};
            #pragma unroll
            for (int i = 0; i < 4; ++i)
                #pragma unroll
                for (int j = 0; j < 4; ++j) acc[i][j] += av[i] * bv[j];
        }
        __syncthreads();
    }
    #pragma unroll
    for (int i = 0; i < 4; ++i) {
        int m = ty * 4 + i;
        #pragma unroll
        for (int j = 0; j < 4; ++j) {
            int n = n0 + tx * 4 + j;
            float v = acc[i][j];
            if (seg == 0)      att2[m * 512 + n] = v + bd[n];
            else if (seg == 1) gate[m * 2048 + n] = sigm(v + bb[n]);
            else if (seg == 2) part[((size_t)5 * BB + m) * 2048 + n] = v;
            else               part[((size_t)0 * BB + m) * 2048 + n] = v;
        }
    }
}

// e scores + softmax -> alpha (one block per b)
__global__ __launch_bounds__(256) void k_escore(const float* __restrict__ att1,
                                                const float* __restrict__ att2,
                                                const float* __restrict__ Wf,
                                                const int* __restrict__ lens, int t,
                                                float* __restrict__ alpha,
                                                float* __restrict__ out_alpha) {
    __shared__ float a2[512], wf[512], es[224], red[256];
    int b = blockIdx.x, tid = threadIdx.x;
    for (int i = tid; i < 512; i += 256) { a2[i] = att2[b * 512 + i]; wf[i] = Wf[i]; }
    __syncthreads();
    int lane = tid & 63, wid = tid >> 6;
    for (int p = wid; p < PP; p += 4) {
        const float* row = att1 + ((size_t)(b * PP + p)) * 512 + lane * 8;
        float4 r0 = *(const float4*)(row);
        float4 r1 = *(const float4*)(row + 4);
        float4 c0 = *(const float4*)(&a2[lane * 8]);
        float4 c1 = *(const float4*)(&a2[lane * 8 + 4]);
        float4 w0 = *(const float4*)(&wf[lane * 8]);
        float4 w1 = *(const float4*)(&wf[lane * 8 + 4]);
        float s = 0.f, v;
        v = r0.x + c0.x; s += (v > 0.f ? v : 0.f) * w0.x;
        v = r0.y + c0.y; s += (v > 0.f ? v : 0.f) * w0.y;
        v = r0.z + c0.z; s += (v > 0.f ? v : 0.f) * w0.z;
        v = r0.w + c0.w; s += (v > 0.f ? v : 0.f) * w0.w;
        v = r1.x + c1.x; s += (v > 0.f ? v : 0.f) * w1.x;
        v = r1.y + c1.y; s += (v > 0.f ? v : 0.f) * w1.y;
        v = r1.z + c1.z; s += (v > 0.f ? v : 0.f) * w1.z;
        v = r1.w + c1.w; s += (v > 0.f ? v : 0.f) * w1.w;
        #pragma unroll
        for (int off = 32; off; off >>= 1) s += __shfl_down(s, off);
        if (lane == 0) es[p] = s;
    }
    __syncthreads();
    float v = (tid < PP) ? es[tid] : -3.4e38f;
    red[tid] = v; __syncthreads();
    for (int s = 128; s; s >>= 1) { if (tid < s) red[tid] = fmaxf(red[tid], red[tid + s]); __syncthreads(); }
    float mx = red[0]; __syncthreads();
    float ev = (tid < PP) ? __expf(v - mx) : 0.f;
    red[tid] = ev; __syncthreads();
    for (int s = 128; s; s >>= 1) { if (tid < s) red[tid] += red[tid + s]; __syncthreads(); }
    float inv = 1.f / red[0];
    if (tid < PP) {
        float al = ev * inv;
        alpha[b * PP + tid] = al;
        bool m = t < (lens[b] - 1);
        out_alpha[((size_t)b * TT + t) * PP + tid] = m ? al : 0.f;
    }
}

// awe from bf16 encoder: 2 elems/thread
__global__ void k_awe16(const ushort* __restrict__ encB, const float* __restrict__ alpha,
                        const float* __restrict__ gate, float* __restrict__ awe) {
    __shared__ float al[PP];
    int b = blockIdx.y;
    int e2 = blockIdx.x * 256 + threadIdx.x;   // pair index 0..1023
    for (int i = threadIdx.x; i < PP; i += 256) al[i] = alpha[b * PP + i];
    __syncthreads();
    const uint* p = (const uint*)(encB + (size_t)b * PP * ENCD) + e2;
    float s0 = 0.f, s1 = 0.f;
    #pragma unroll 4
    for (int i = 0; i < PP; ++i) {
        uint v = p[(size_t)i * (ENCD / 2)];
        float a = al[i];
        s0 += a * __uint_as_float(v << 16);
        s1 += a * __uint_as_float(v & 0xffff0000u);
    }
    int e = e2 * 2;
    awe[b * 2048 + e]     = s0 * gate[b * 2048 + e];
    awe[b * 2048 + e + 1] = s1 * gate[b * 2048 + e + 1];
}

// f32 fallback awe
__global__ void k_awe(const float* __restrict__ enc, const float* __restrict__ alpha,
                      const float* __restrict__ gate, float* __restrict__ awe) {
    __shared__ float al[PP];
    int b = blockIdx.y;
    int e = blockIdx.x * 256 + threadIdx.x;
    for (int i = threadIdx.x; i < PP; i += 256) al[i] = alpha[b * PP + i];
    __syncthreads();
    const float* p = enc + (size_t)b * PP * ENCD + e;
    float s = 0.f;
    #pragma unroll 4
    for (int i = 0; i < PP; ++i) s += al[i] * p[(size_t)i * ENCD];
    awe[b * ENCD + e] = s * gate[b * ENCD + e];
}

// P4: awe@W_ih[512+kc*512 ...] -> part[1+kc], grid (32, 4)
__global__ __launch_bounds__(256) void k_gates_awe(const float* __restrict__ Wih,
        const float* __restrict__ awe, float* __restrict__ part) {
    __shared__ alignas(16) float As[32][68];
    __shared__ alignas(16) float Bs[32][68];
    const int n0 = blockIdx.x * 64;
    const int kc = blockIdx.y;                 // 0..3
    const int tid = threadIdx.x, tx = tid & 15, ty = tid >> 4;
    float acc[4][4] = {};
    for (int k0 = 0; k0 < 512; k0 += 32) {
        #pragma unroll
        for (int p = 0; p < 2; ++p) {
            int c = p * 256 + tid;
            int m = c >> 3, k4 = (c & 7) * 4;
            float4 v = *(const float4*)(awe + m * 2048 + kc * 512 + k0 + k4);
            As[k4 + 0][m] = v.x; As[k4 + 1][m] = v.y; As[k4 + 2][m] = v.z; As[k4 + 3][m] = v.w;
            int kb = c >> 4, n4 = (c & 15) * 4;
            float4 w = *(const float4*)(Wih + (size_t)(512 + kc * 512 + k0 + kb) * 2048 + n0 + n4);
            *(float4*)&Bs[kb][n4] = w;
        }
        __syncthreads();
        #pragma unroll 8
        for (int k = 0; k < 32; ++k) {
            float4 a = *(const float4*)&As[k][ty * 4];
            float4 b = *(const float4*)&Bs[k][tx * 4];
            float av[4] = {a.x, a.y, a.z, a.w}, bv[4] = {b.x, b.y, b.z, b.w};
            #pragma unroll
            for (int i = 0; i < 4; ++i)
                #pragma unroll
                for (int j = 0; j < 4; ++j) acc[i][j] += av[i] * bv[j];
        }
        __syncthreads();
    }
    #pragma unroll
    for (int i = 0; i < 4; ++i) {
        int m = ty * 4 + i;
        #pragma unroll
        for (int j = 0; j < 4; ++j) {
            int n = n0 + tx * 4 + j;
            part[((size_t)(1 + kc) * BB + m) * 2048 + n] = acc[i][j];
        }
    }
}

// LSTM pointwise + memory attention + h/c carry (one block per b)
__global__ __launch_bounds__(256) void k_memattn(const float* __restrict__ part,
                                                 const float* __restrict__ bih,
                                                 const float* __restrict__ bhh,
                                                 const int* __restrict__ lens, int t,
                                                 const float* __restrict__ memB,
                                                 float* __restrict__ h, float* __restrict__ c,
                                                 float* __restrict__ hnew, ushort* __restrict__ hB) {
    __shared__ float hs[512], sims[128], red[256], ps[128];
    int b = blockIdx.x, tid = threadIdx.x;
    bool msk = t < (lens[b] - 1);
    for (int j = tid; j < 512; j += 256) {
        float g[4];
        #pragma unroll
        for (int q = 0; q < 4; ++q) {
            int col = q * 512 + j;
            float s = bih[col] + bhh[col];
            #pragma unroll
            for (int kc = 0; kc < 6; ++kc) s += part[((size_t)kc * BB + b) * 2048 + col];
            g[q] = s;
        }
        float gi = sigm(g[0]), gf = sigm(g[1]), gg = tanh_f(g[2]), go = sigm(g[3]);
        float cold = c[b * 512 + j];
        float cn = gf * cold + gi * gg;
        c[b * 512 + j] = msk ? cn : cold;
        hs[j] = go * tanh_f(cn);
    }
    __syncthreads();
    int lane = tid & 63, wid = tid >> 6;
    for (int m = wid * 32; m < wid * 32 + 32; ++m) {
        const float* r = memB + (size_t)m * 512 + lane * 8;
        float4 r0 = *(const float4*)(r);
        float4 r1 = *(const float4*)(r + 4);
        float4 h0 = *(const float4*)(&hs[lane * 8]);
        float4 h1 = *(const float4*)(&hs[lane * 8 + 4]);
        float s = r0.x * h0.x + r0.y * h0.y + r0.z * h0.z + r0.w * h0.w
                + r1.x * h1.x + r1.y * h1.y + r1.z * h1.z + r1.w * h1.w;
        #pragma unroll
        for (int off = 32; off; off >>= 1) s += __shfl_down(s, off);
        if (lane == 0) sims[m] = s;
    }
    __syncthreads();
    float v = (tid < 128) ? sims[tid] : -3.4e38f;
    red[tid] = v; __syncthreads();
    for (int s = 128; s; s >>= 1) { if (tid < s) red[tid] = fmaxf(red[tid], red[tid + s]); __syncthreads(); }
    float mx = red[0]; __syncthreads();
    float ev = (tid < 128) ? __expf(v - mx) : 0.f;
    red[tid] = ev; __syncthreads();
    for (int s = 128; s; s >>= 1) { if (tid < s) red[tid] += red[tid + s]; __syncthreads(); }
    if (tid < 128) ps[tid] = ev / red[0];
    __syncthreads();
    for (int d = tid; d < 512; d += 256) {
        float s = 0.f;
        #pragma unroll 4
        for (int m = 0; m < 128; ++m) s += ps[m] * memB[(size_t)m * 512 + d];
        float hn = hs[d] + s;
        hnew[b * 512 + d] = hn;
        hB[b * 512 + d] = f2bf(hn);
        float hold = h[b * 512 + d];
        h[b * 512 + d] = msk ? hn : hold;
    }
}

// preds via bf16 MFMA: M=64, N-tile=256 (4 waves x 64), K=512
__global__ __launch_bounds__(256) void k_preds_mfma(const ushort* __restrict__ hB,
        const ushort* __restrict__ WfcT, const float* __restrict__ bfc,
        const int* __restrict__ lens, int t, float* __restrict__ out) {
    __shared__ alignas(16) ushort As[64 * 64];
    __shared__ alignas(16) ushort Bs[256 * 64];
    const int n0 = blockIdx.x * 256;
    const int tid = threadIdx.x, wid = tid >> 6, lane = tid & 63;
    f32x4 acc[4][4] = {};
    for (int k0 = 0; k0 < 512; k0 += 64) {
        #pragma unroll
        for (int p = 0; p < 2; ++p) {
            int c = p * 256 + tid;
            int r = c >> 3, cc = c & 7;
            float4 v = *(const float4*)(hB + r * 512 + k0 + cc * 8);
            *(float4*)(As + r * 64 + ((cc ^ (r & 7)) * 8)) = v;
        }
        #pragma unroll
        for (int p = 0; p < 8; ++p) {
            int c = p * 256 + tid;
            int r = c >> 3, cc = c & 7;
            float4 v = *(const float4*)(WfcT + (size_t)(n0 + r) * 512 + k0 + cc * 8);
            *(float4*)(Bs + r * 64 + ((cc ^ (r & 7)) * 8)) = v;
        }
        __syncthreads();
        #pragma unroll
        for (int kk = 0; kk < 2; ++kk) {
            int ci = kk * 4 + (lane >> 4);
            bf16x8 afrag[4], bfrag[4];
            #pragma unroll
            for (int m = 0; m < 4; ++m) {
                int row = m * 16 + (lane & 15);
                afrag[m] = *(const bf16x8*)(As + row * 64 + ((ci ^ (row & 7)) * 8));
            }
            #pragma unroll
            for (int n = 0; n < 4; ++n) {
                int col = wid * 64 + n * 16 + (lane & 15);
                bfrag[n] = *(const bf16x8*)(Bs + col * 64 + ((ci ^ (col & 7)) * 8));
            }
            #pragma unroll
            for (int m = 0; m < 4; ++m)
                #pragma unroll
                for (int n = 0; n < 4; ++n)
                    acc[m][n] = __builtin_amdgcn_mfma_f32_16x16x32_bf16(afrag[m], bfrag[n], acc[m][n], 0, 0, 0);
        }
        __syncthreads();
    }
    #pragma unroll
    for (int m = 0; m < 4; ++m) {
        int rb = m * 16 + (lane >> 4) * 4;
        #pragma unroll
        for (int n = 0; n < 4; ++n) {
            int col = n0 + wid * 64 + n * 16 + (lane & 15);
            if (col < VV) {
                float bv = bfc[col];
                #pragma unroll
                for (int r = 0; r < 4; ++r) {
                    int mm = rb + r;
                    bool msk = t < (lens[mm] - 1);
                    out[((size_t)mm * TT + t) * VV + col] = msk ? (acc[m][n][r] + bv) : 0.f;
                }
            }
        }
    }
}

// f32 fallback preds
__global__ __launch_bounds__(256) void k_preds(const float* __restrict__ hnew,
                        const float* __restrict__ Wfc,
                        const float* __restrict__ bfc, const int* __restrict__ lens, int t,
                        float* __restrict__ out) {
    __shared__ alignas(16) float As[32][68];
    __shared__ alignas(16) float Bs[32][68];
    const int n0 = blockIdx.x * 64;
    const int tid = threadIdx.x, tx = tid & 15, ty = tid >> 4;
    float acc[4][4] = {};
    for (int k0 = 0; k0 < 512; k0 += 32) {
        #pragma unroll
        for (int p = 0; p < 2; ++p) {
            int c = p * 256 + tid;
            int m = c >> 3, k4 = (c & 7) * 4;
            float4 v = *(const float4*)(hnew + m * 512 + k0 + k4);
            As[k4 + 0][m] = v.x; As[k4 + 1][m] = v.y; As[k4 + 2][m] = v.z; As[k4 + 3][m] = v.w;
            int kb = c >> 4, n4 = (c & 15) * 4;
            int n = n0 + n4;
            float4 w = {0.f, 0.f, 0.f, 0.f};
            if (n < VV) w = *(const float4*)(Wfc + (size_t)(k0 + kb) * VV + n);
            *(float4*)&Bs[kb][n4] = w;
        }
        __syncthreads();
        #pragma unroll 8
        for (int k = 0; k < 32; ++k) {
            float4 a = *(const float4*)&As[k][ty * 4];
            float4 b = *(const float4*)&Bs[k][tx * 4];
            float av[4] = {a.x, a.y, a.z, a.w}, bv[4] = {b.x, b.y, b.z, b.w};
            #pragma unroll
            for (int i = 0; i < 4; ++i)
                #pragma unroll
                for (int j = 0; j < 4; ++j) acc[i][j] += av[i] * bv[j];
        }
        __syncthreads();
    }
    #pragma unroll
    for (int i = 0; i < 4; ++i) {
        int m = ty * 4 + i;
        bool msk = t < (lens[m] - 1);
        #pragma unroll
        for (int j = 0; j < 4; ++j) {
            int n = n0 + tx * 4 + j;
            if (n < VV) {
                float vv = msk ? (acc[i][j] + bfc[n]) : 0.f;
                out[((size_t)m * TT + t) * VV + n] = vv;
            }
        }
    }
}

// ---------------- launch ----------------

extern "C" void kernel_launch(void* const* d_in, const int* in_sizes, int n_in,
                              void* d_out, int out_size, void* d_ws, size_t ws_size,
                              hipStream_t stream) {
    const float* enc     = (const float*)d_in[0];
    const int*   caps    = (const int*)d_in[1];
    const int*   lens    = (const int*)d_in[2];
    const float* emb     = (const float*)d_in[3];
    const float* W_enc   = (const float*)d_in[4];
    const float* b_enc   = (const float*)d_in[5];
    const float* W_dec   = (const float*)d_in[6];
    const float* b_dec   = (const float*)d_in[7];
    const float* W_full  = (const float*)d_in[8];
    const float* W_inith = (const float*)d_in[10];
    const float* b_inith = (const float*)d_in[11];
    const float* W_initc = (const float*)d_in[12];
    const float* b_initc = (const float*)d_in[13];
    const float* W_beta  = (const float*)d_in[14];
    const float* b_beta  = (const float*)d_in[15];
    const float* W_ih    = (const float*)d_in[16];
    const float* b_ih    = (const float*)d_in[17];
    const float* W_hh    = (const float*)d_in[18];
    const float* b_hh    = (const float*)d_in[19];
    const float* memB    = (const float*)d_in[20];
    const float* W_fc    = (const float*)d_in[21];
    const float* b_fc    = (const float*)d_in[22];

    float* out = (float*)d_out;
    float* preds_out  = out;
    float* declen_out = out + (size_t)BB * TT * VV;
    float* alpha_out  = declen_out + BB;

    float* ws   = (float*)d_ws;
    float* att1 = ws;  ws += (size_t)12544 * 512;
    float* mean = ws;  ws += BB * ENCD;
    float* h    = ws;  ws += BB * DECD;
    float* c    = ws;  ws += BB * DECD;
    float* att2 = ws;  ws += BB * 512;
    float* gate = ws;  ws += BB * ENCD;
    float* alpha= ws;  ws += BB * PP;
    float* awe  = ws;  ws += BB * ENCD;
    float* hnew = ws;  ws += BB * DECD;
    float* part = ws;  ws += (size_t)6 * BB * 2048;
    float* ipart= ws;  ws += (size_t)8 * BB * 512;
    ushort* hB  = (ushort*)ws; ws += BB * DECD / 2;
    ushort* encB  = (ushort*)ws;
    ushort* WencT = encB + (size_t)12544 * 2048;
    ushort* WfcT  = WencT + (size_t)512 * 2048;

    size_t need = ((char*)(WfcT + (size_t)10240 * 512)) - ((char*)d_ws);
    bool use_mfma = ws_size >= need;

    k_mean<<<512, 256, 0, stream>>>(enc, mean);
    k_ipart<<<dim3(8, 4, 2), 256, 0, stream>>>(mean, W_inith, W_initc, ipart);
    k_ifin<<<256, 256, 0, stream>>>(ipart, b_inith, b_initc, h, c);
    k_declen<<<1, 64, 0, stream>>>(lens, declen_out);

    if (use_mfma) {
        k_cvt<<<(12544 * 2048 / 4 + 255) / 256, 256, 0, stream>>>(enc, encB, 12544 * 2048 / 4);
        k_tcvt<<<dim3(32, 8), 256, 0, stream>>>(W_enc, WencT, 2048, 512);
        k_tcvt<<<dim3(8, 160), 256, 0, stream>>>(W_fc, WfcT, 512, VV);
        k_att1_mfma<<<dim3(8, 98), 256, 0, stream>>>(encB, WencT, b_enc, att1);
    } else {
        k_att1<<<dim3(4, 98), 256, 0, stream>>>(enc, W_enc, b_enc, att1);
    }

    for (int t = 0; t < TT; ++t) {
        k_hgemm<<<104, 256, 0, stream>>>(h, emb, caps, t, W_dec, b_dec, W_beta, b_beta,
                                         W_hh, W_ih, att2, gate, part);
        k_escore<<<64, 256, 0, stream>>>(att1, att2, W_full, lens, t, alpha, alpha_out);
        if (use_mfma) k_awe16<<<dim3(4, 64), 256, 0, stream>>>(encB, alpha, gate, awe);
        else          k_awe<<<dim3(8, 64), 256, 0, stream>>>(enc, alpha, gate, awe);
        k_gates_awe<<<dim3(32, 4), 256, 0, stream>>>(W_ih, awe, part);
        k_memattn<<<64, 256, 0, stream>>>(part, b_ih, b_hh, lens, t, memB, h, c, hnew, hB);
        if (use_mfma) k_preds_mfma<<<40, 256, 0, stream>>>(hB, WfcT, b_fc, lens, t, preds_out);
        else          k_preds<<<157, 256, 0, stream>>>(hnew, W_fc, b_fc, lens, t, preds_out);
    }
}

// Round 5
// 3670.894 us; speedup vs baseline: 2.1624x; 1.0772x over previous
//
#include <hip/hip_runtime.h>

#define BB   64
#define PP   196
#define ENCD 2048
#define DECD 512
#define VV   10000
#define TT   21
#define KIH  2560   // (EMB + ENC) rows of W_ih

typedef __attribute__((ext_vector_type(8))) short bf16x8;
typedef __attribute__((ext_vector_type(4))) float f32x4;

__device__ __forceinline__ float sigm(float x)   { return 1.f / (1.f + __expf(-x)); }
__device__ __forceinline__ float tanh_f(float x) { return 1.f - 2.f / (1.f + __expf(2.f * x)); }
__device__ __forceinline__ ushort f2bf(float x) {
    unsigned u = __float_as_uint(x);
    unsigned r = (u + 0x7FFFu + ((u >> 16) & 1u)) >> 16;
    return (ushort)r;
}
__device__ __forceinline__ float bf2f(short u) {
    return __uint_as_float(((unsigned)(ushort)u) << 16);
}
union U8 { float4 f4; ushort u[8]; };

// ---------------- setup kernels ----------------

__global__ void k_mean(const float* __restrict__ enc, float* __restrict__ mean) {
    int idx = blockIdx.x * 256 + threadIdx.x;      // 64*2048
    int b = idx >> 11, e = idx & 2047;
    const float* p = enc + (size_t)b * PP * ENCD + e;
    float s = 0.f;
    #pragma unroll 4
    for (int i = 0; i < PP; ++i) s += p[(size_t)i * ENCD];
    mean[idx] = s * (1.f / 196.f);
}

// h0/c0 partial GEMM (f32): grid (8 ntiles, 4 kc, 2 mat), tile 64x64
__global__ __launch_bounds__(256) void k_ipart(const float* __restrict__ mean,
        const float* __restrict__ Wh, const float* __restrict__ Wc,
        float* __restrict__ ipart) {
    __shared__ alignas(16) float As[32][68];
    __shared__ alignas(16) float Bs[32][68];
    const int n0 = blockIdx.x * 64;
    const int kc = blockIdx.y;
    const int mat = blockIdx.z;
    const float* Bp = mat ? Wc : Wh;
    const int tid = threadIdx.x, tx = tid & 15, ty = tid >> 4;
    float acc[4][4] = {};
    for (int k0 = 0; k0 < 512; k0 += 32) {
        #pragma unroll
        for (int p = 0; p < 2; ++p) {
            int c = p * 256 + tid;
            int m = c >> 3, k4 = (c & 7) * 4;
            float4 v = *(const float4*)(mean + m * 2048 + kc * 512 + k0 + k4);
            As[k4 + 0][m] = v.x; As[k4 + 1][m] = v.y; As[k4 + 2][m] = v.z; As[k4 + 3][m] = v.w;
            int kb = c >> 4, n4 = (c & 15) * 4;
            float4 w = *(const float4*)(Bp + (size_t)(kc * 512 + k0 + kb) * 512 + n0 + n4);
            *(float4*)&Bs[kb][n4] = w;
        }
        __syncthreads();
        #pragma unroll 8
        for (int k = 0; k < 32; ++k) {
            float4 a = *(const float4*)&As[k][ty * 4];
            float4 b = *(const float4*)&Bs[k][tx * 4];
            float av[4] = {a.x, a.y, a.z, a.w}, bv[4] = {b.x, b.y, b.z, b.w};
            #pragma unroll
            for (int i = 0; i < 4; ++i)
                #pragma unroll
                for (int j = 0; j < 4; ++j) acc[i][j] += av[i] * bv[j];
        }
        __syncthreads();
    }
    #pragma unroll
    for (int i = 0; i < 4; ++i) {
        int m = ty * 4 + i;
        #pragma unroll
        for (int j = 0; j < 4; ++j) {
            int n = n0 + tx * 4 + j;
            ipart[((size_t)(mat * 4 + kc) * BB + m) * 512 + n] = acc[i][j];
        }
    }
}

__global__ void k_ifin(const float* __restrict__ ipart,
                       const float* __restrict__ bh, const float* __restrict__ bc,
                       float* __restrict__ h, float* __restrict__ c, ushort* __restrict__ hB) {
    int idx = blockIdx.x * 256 + threadIdx.x;     // 2*64*512
    int mat = idx >> 15, rem = idx & 32767;
    int b = rem >> 9, d = rem & 511;
    float s = 0.f;
    #pragma unroll
    for (int kc = 0; kc < 4; ++kc) s += ipart[((size_t)(mat * 4 + kc) * BB + b) * 512 + d];
    if (mat) c[rem] = s + bc[d];
    else { float v = s + bh[d]; h[rem] = v; hB[rem] = f2bf(v); }
}

// f32->bf16 elementwise
__global__ void k_cvt(const float* __restrict__ in, ushort* __restrict__ out, int n4) {
    int i = blockIdx.x * 256 + threadIdx.x;
    if (i >= n4) return;
    float4 v = ((const float4*)in)[i];
    ushort4 o; o.x = f2bf(v.x); o.y = f2bf(v.y); o.z = f2bf(v.z); o.w = f2bf(v.w);
    ((ushort4*)out)[i] = o;
}

// all weight transposes in one launch: in[K][N] f32 -> out[Npad][K] bf16
__global__ __launch_bounds__(256) void k_tcvt_all(
        const float* __restrict__ Wenc, const float* __restrict__ Wdec,
        const float* __restrict__ Wbeta, const float* __restrict__ Whh,
        const float* __restrict__ Wih, const float* __restrict__ Wfc,
        ushort* __restrict__ WencT, ushort* __restrict__ WdecT,
        ushort* __restrict__ WbetaT, ushort* __restrict__ WhhT,
        ushort* __restrict__ WihT, ushort* __restrict__ WfcT) {
    __shared__ float lds[64 * 65];
    int l = blockIdx.x;
    const float* in; ushort* out; int K, N, KT;
    if (l < 256)       { in = Wenc;  out = WencT;  K = 2048; N = 512;   KT = 32; }
    else if (l < 320)  { l -= 256;  in = Wdec;  out = WdecT;  K = 512;  N = 512;   KT = 8; }
    else if (l < 576)  { l -= 320;  in = Wbeta; out = WbetaT; K = 512;  N = 2048;  KT = 8; }
    else if (l < 832)  { l -= 576;  in = Whh;   out = WhhT;   K = 512;  N = 2048;  KT = 8; }
    else if (l < 2112) { l -= 832;  in = Wih;   out = WihT;   K = KIH;  N = 2048;  KT = 40; }
    else               { l -= 2112; in = Wfc;   out = WfcT;   K = 512;  N = 10000; KT = 8; }
    const int k0 = (l % KT) * 64, n0 = (l / KT) * 64;
    const int tid = threadIdx.x;
    for (int i = tid; i < 4096; i += 256) {
        int kk = i >> 6, nn = i & 63;
        float v = 0.f;
        if (n0 + nn < N) v = in[(size_t)(k0 + kk) * N + n0 + nn];
        lds[nn * 65 + kk] = v;
    }
    __syncthreads();
    for (int i = tid; i < 4096; i += 256) {
        int nn = i >> 6, kk = i & 63;
        out[(size_t)(n0 + nn) * K + k0 + kk] = f2bf(lds[nn * 65 + kk]);
    }
}

// att1B = bf16(encB @ WencT^T + bias). tile M=64 x N=512(full), 8 waves, BK=64.
__global__ __launch_bounds__(512) void k_att1_wide(const ushort* __restrict__ A,
        const ushort* __restrict__ Bt, const float* __restrict__ bias,
        ushort* __restrict__ C) {
    __shared__ alignas(16) ushort As[64 * 64];
    __shared__ alignas(16) ushort Bs[512 * 64];
    const int m0 = blockIdx.x * 64;
    const int tid = threadIdx.x, wid = tid >> 6, lane = tid & 63;
    f32x4 acc[4][4] = {};
    for (int k0 = 0; k0 < 2048; k0 += 64) {
        {
            int r = tid >> 3, cc = tid & 7;
            float4 v = *(const float4*)(A + (size_t)(m0 + r) * 2048 + k0 + cc * 8);
            *(float4*)(As + r * 64 + ((cc ^ (r & 7)) * 8)) = v;
        }
        #pragma unroll
        for (int p = 0; p < 8; ++p) {
            int c = p * 512 + tid;
            int r = c >> 3, cc = c & 7;
            float4 v = *(const float4*)(Bt + (size_t)r * 2048 + k0 + cc * 8);
            *(float4*)(Bs + r * 64 + ((cc ^ (r & 7)) * 8)) = v;
        }
        __syncthreads();
        #pragma unroll
        for (int kk = 0; kk < 2; ++kk) {
            int ci = kk * 4 + (lane >> 4);
            bf16x8 afrag[4], bfrag[4];
            #pragma unroll
            for (int m = 0; m < 4; ++m) {
                int row = m * 16 + (lane & 15);
                afrag[m] = *(const bf16x8*)(As + row * 64 + ((ci ^ (row & 7)) * 8));
            }
            #pragma unroll
            for (int n = 0; n < 4; ++n) {
                int col = wid * 64 + n * 16 + (lane & 15);
                bfrag[n] = *(const bf16x8*)(Bs + col * 64 + ((ci ^ (col & 7)) * 8));
            }
            #pragma unroll
            for (int m = 0; m < 4; ++m)
                #pragma unroll
                for (int n = 0; n < 4; ++n)
                    acc[m][n] = __builtin_amdgcn_mfma_f32_16x16x32_bf16(afrag[m], bfrag[n], acc[m][n], 0, 0, 0);
        }
        __syncthreads();
    }
    #pragma unroll
    for (int m = 0; m < 4; ++m) {
        int rb = m0 + m * 16 + (lane >> 4) * 4;
        #pragma unroll
        for (int n = 0; n < 4; ++n) {
            int col = wid * 64 + n * 16 + (lane & 15);
            float bv = bias[col];
            #pragma unroll
            for (int r = 0; r < 4; ++r)
                C[(size_t)(rb + r) * 512 + col] = f2bf(acc[m][n][r] + bv);
        }
    }
}

__global__ void k_declen(const int* __restrict__ lens, float* __restrict__ out) {
    int b = threadIdx.x;
    if (b < BB) out[b] = (float)(lens[b] - 1);
}

// ---------------- per-step kernels ----------------

// P1: bf16 MFMA, 18 blocks, tile M=64 x N=256.
// bx 0-1:  att2 = h@W_dec + bd                       (K=512)
// bx 2-9:  gate = sigm(h@W_beta + bb)                (K=512)
// bx 10-17: part0 = h@W_hh + emb_t@W_ih[0:512]       (K=1024 fused)
__global__ __launch_bounds__(256) void k_hgemm(const ushort* __restrict__ hB,
        const float* __restrict__ emb, const int* __restrict__ caps, int t,
        const ushort* __restrict__ WdecT, const float* __restrict__ bd,
        const ushort* __restrict__ WbetaT, const float* __restrict__ bb,
        const ushort* __restrict__ WhhT, const ushort* __restrict__ WihT,
        float* __restrict__ att2, float* __restrict__ gate, float* __restrict__ part) {
    __shared__ alignas(16) ushort As[64 * 64];
    __shared__ alignas(16) ushort Bs[256 * 64];
    __shared__ int capsh[64];
    const int bx = blockIdx.x;
    int seg, n0;
    if (bx < 2)       { seg = 0; n0 = bx * 256; }
    else if (bx < 10) { seg = 1; n0 = (bx - 2) * 256; }
    else              { seg = 2; n0 = (bx - 10) * 256; }
    const int tid = threadIdx.x, wid = tid >> 6, lane = tid & 63;
    if (tid < 64) capsh[tid] = caps[tid * 22 + t];
    __syncthreads();
    const int KSEG = (seg == 2) ? 1024 : 512;
    f32x4 acc[4][4] = {};
    for (int k0 = 0; k0 < KSEG; k0 += 64) {
        const bool second = k0 >= 512;
        #pragma unroll
        for (int p = 0; p < 2; ++p) {
            int c = p * 256 + tid;
            int r = c >> 3, cc = c & 7;
            if (!second) {
                float4 v = *(const float4*)(hB + r * 512 + k0 + cc * 8);
                *(float4*)(As + r * 64 + ((cc ^ (r & 7)) * 8)) = v;
            } else {
                const float* er = emb + (size_t)capsh[r] * 512 + (k0 - 512) + cc * 8;
                float4 v0 = *(const float4*)er;
                float4 v1 = *(const float4*)(er + 4);
                U8 pk;
                pk.u[0] = f2bf(v0.x); pk.u[1] = f2bf(v0.y); pk.u[2] = f2bf(v0.z); pk.u[3] = f2bf(v0.w);
                pk.u[4] = f2bf(v1.x); pk.u[5] = f2bf(v1.y); pk.u[6] = f2bf(v1.z); pk.u[7] = f2bf(v1.w);
                *(float4*)(As + r * 64 + ((cc ^ (r & 7)) * 8)) = pk.f4;
            }
        }
        #pragma unroll
        for (int p = 0; p < 8; ++p) {
            int c = p * 256 + tid;
            int r = c >> 3, cc = c & 7;
            int nsrc = n0 + r;
            const ushort* brow;
            if (seg == 0)      brow = WdecT + (size_t)nsrc * 512 + k0 + cc * 8;
            else if (seg == 1) brow = WbetaT + (size_t)nsrc * 512 + k0 + cc * 8;
            else brow = second ? (WihT + (size_t)nsrc * KIH + (k0 - 512) + cc * 8)
                               : (WhhT + (size_t)nsrc * 512 + k0 + cc * 8);
            float4 v = *(const float4*)brow;
            *(float4*)(Bs + r * 64 + ((cc ^ (r & 7)) * 8)) = v;
        }
        __syncthreads();
        #pragma unroll
        for (int kk = 0; kk < 2; ++kk) {
            int ci = kk * 4 + (lane >> 4);
            bf16x8 afrag[4], bfrag[4];
            #pragma unroll
            for (int m = 0; m < 4; ++m) {
                int row = m * 16 + (lane & 15);
                afrag[m] = *(const bf16x8*)(As + row * 64 + ((ci ^ (row & 7)) * 8));
            }
            #pragma unroll
            for (int n = 0; n < 4; ++n) {
                int col = wid * 64 + n * 16 + (lane & 15);
                bfrag[n] = *(const bf16x8*)(Bs + col * 64 + ((ci ^ (col & 7)) * 8));
            }
            #pragma unroll
            for (int m = 0; m < 4; ++m)
                #pragma unroll
                for (int n = 0; n < 4; ++n)
                    acc[m][n] = __builtin_amdgcn_mfma_f32_16x16x32_bf16(afrag[m], bfrag[n], acc[m][n], 0, 0, 0);
        }
        __syncthreads();
    }
    #pragma unroll
    for (int m = 0; m < 4; ++m) {
        int rb = m * 16 + (lane >> 4) * 4;
        #pragma unroll
        for (int n = 0; n < 4; ++n) {
            int colL = wid * 64 + n * 16 + (lane & 15);
            int col = n0 + colL;
            #pragma unroll
            for (int r = 0; r < 4; ++r) {
                int row = rb + r;
                float v = acc[m][n][r];
                if (seg == 0)      att2[row * 512 + col] = v + bd[col];
                else if (seg == 1) gate[row * 2048 + col] = sigm(v + bb[col]);
                else               part[(size_t)row * 2048 + col] = v;
            }
        }
    }
}

// e scores + softmax -> alpha (one block per b); att1 in bf16
__global__ __launch_bounds__(256) void k_escore(const ushort* __restrict__ att1B,
                                                const float* __restrict__ att2,
                                                const float* __restrict__ Wf,
                                                const int* __restrict__ lens, int t,
                                                float* __restrict__ alpha,
                                                float* __restrict__ out_alpha) {
    __shared__ float a2[512], wf[512], es[224], red[256];
    int b = blockIdx.x, tid = threadIdx.x;
    for (int i = tid; i < 512; i += 256) { a2[i] = att2[b * 512 + i]; wf[i] = Wf[i]; }
    __syncthreads();
    int lane = tid & 63, wid = tid >> 6;
    for (int p = wid; p < PP; p += 4) {
        bf16x8 rv = *(const bf16x8*)(att1B + ((size_t)(b * PP + p)) * 512 + lane * 8);
        float s = 0.f;
        #pragma unroll
        for (int j = 0; j < 8; ++j) {
            float v = bf2f(rv[j]) + a2[lane * 8 + j];
            s += (v > 0.f ? v : 0.f) * wf[lane * 8 + j];
        }
        #pragma unroll
        for (int off = 32; off; off >>= 1) s += __shfl_down(s, off);
        if (lane == 0) es[p] = s;
    }
    __syncthreads();
    float v = (tid < PP) ? es[tid] : -3.4e38f;
    red[tid] = v; __syncthreads();
    for (int s = 128; s; s >>= 1) { if (tid < s) red[tid] = fmaxf(red[tid], red[tid + s]); __syncthreads(); }
    float mx = red[0]; __syncthreads();
    float ev = (tid < PP) ? __expf(v - mx) : 0.f;
    red[tid] = ev; __syncthreads();
    for (int s = 128; s; s >>= 1) { if (tid < s) red[tid] += red[tid + s]; __syncthreads(); }
    float inv = 1.f / red[0];
    if (tid < PP) {
        float al = ev * inv;
        alpha[b * PP + tid] = al;
        bool m = t < (lens[b] - 1);
        out_alpha[((size_t)b * TT + t) * PP + tid] = m ? al : 0.f;
    }
}

// aweB = bf16(gate * (alpha @ enc_b)); 2 elems/thread
__global__ void k_awe16(const ushort* __restrict__ encB, const float* __restrict__ alpha,
                        const float* __restrict__ gate, uint* __restrict__ aweB) {
    __shared__ float al[PP];
    int b = blockIdx.y;
    int e2 = blockIdx.x * 256 + threadIdx.x;   // pair index 0..1023
    for (int i = threadIdx.x; i < PP; i += 256) al[i] = alpha[b * PP + i];
    __syncthreads();
    const uint* p = (const uint*)(encB + (size_t)b * PP * ENCD) + e2;
    float s0 = 0.f, s1 = 0.f;
    #pragma unroll 7
    for (int i = 0; i < PP; ++i) {
        uint v = p[(size_t)i * (ENCD / 2)];
        float a = al[i];
        s0 += a * __uint_as_float(v << 16);
        s1 += a * __uint_as_float(v & 0xffff0000u);
    }
    int e = e2 * 2;
    float g0 = s0 * gate[b * 2048 + e];
    float g1 = s1 * gate[b * 2048 + e + 1];
    aweB[b * 1024 + e2] = (uint)f2bf(g0) | ((uint)f2bf(g1) << 16);
}

// P4: part[1+kc] = aweB @ W_ih[512+kc*1024 .. ] ; grid (8, 2), K=1024
__global__ __launch_bounds__(256) void k_gawe(const ushort* __restrict__ aweB,
        const ushort* __restrict__ WihT, float* __restrict__ part) {
    __shared__ alignas(16) ushort As[64 * 64];
    __shared__ alignas(16) ushort Bs[256 * 64];
    const int n0 = blockIdx.x * 256;
    const int kc = blockIdx.y;
    const int tid = threadIdx.x, wid = tid >> 6, lane = tid & 63;
    f32x4 acc[4][4] = {};
    for (int k0 = 0; k0 < 1024; k0 += 64) {
        #pragma unroll
        for (int p = 0; p < 2; ++p) {
            int c = p * 256 + tid;
            int r = c >> 3, cc = c & 7;
            float4 v = *(const float4*)(aweB + r * 2048 + kc * 1024 + k0 + cc * 8);
            *(float4*)(As + r * 64 + ((cc ^ (r & 7)) * 8)) = v;
        }
        #pragma unroll
        for (int p = 0; p < 8; ++p) {
            int c = p * 256 + tid;
            int r = c >> 3, cc = c & 7;
            float4 v = *(const float4*)(WihT + (size_t)(n0 + r) * KIH + 512 + kc * 1024 + k0 + cc * 8);
            *(float4*)(Bs + r * 64 + ((cc ^ (r & 7)) * 8)) = v;
        }
        __syncthreads();
        #pragma unroll
        for (int kk = 0; kk < 2; ++kk) {
            int ci = kk * 4 + (lane >> 4);
            bf16x8 afrag[4], bfrag[4];
            #pragma unroll
            for (int m = 0; m < 4; ++m) {
                int row = m * 16 + (lane & 15);
                afrag[m] = *(const bf16x8*)(As + row * 64 + ((ci ^ (row & 7)) * 8));
            }
            #pragma unroll
            for (int n = 0; n < 4; ++n) {
                int col = wid * 64 + n * 16 + (lane & 15);
                bfrag[n] = *(const bf16x8*)(Bs + col * 64 + ((ci ^ (col & 7)) * 8));
            }
            #pragma unroll
            for (int m = 0; m < 4; ++m)
                #pragma unroll
                for (int n = 0; n < 4; ++n)
                    acc[m][n] = __builtin_amdgcn_mfma_f32_16x16x32_bf16(afrag[m], bfrag[n], acc[m][n], 0, 0, 0);
        }
        __syncthreads();
    }
    #pragma unroll
    for (int m = 0; m < 4; ++m) {
        int rb = m * 16 + (lane >> 4) * 4;
        #pragma unroll
        for (int n = 0; n < 4; ++n) {
            int col = n0 + wid * 64 + n * 16 + (lane & 15);
            #pragma unroll
            for (int r = 0; r < 4; ++r)
                part[((size_t)(1 + kc) * BB + rb + r) * 2048 + col] = acc[m][n][r];
        }
    }
}

// LSTM pointwise + memory attention + carry; writes h,c (masked), hB, histB
__global__ __launch_bounds__(256) void k_memattn(const float* __restrict__ part,
        const float* __restrict__ bih, const float* __restrict__ bhh,
        const int* __restrict__ lens, int t, const float* __restrict__ memB,
        float* __restrict__ h, float* __restrict__ c,
        ushort* __restrict__ hB, ushort* __restrict__ histB) {
    __shared__ float hs[512], sims[128], red[256], ps[128];
    int b = blockIdx.x, tid = threadIdx.x;
    bool msk = t < (lens[b] - 1);
    for (int j = tid; j < 512; j += 256) {
        float g[4];
        #pragma unroll
        for (int q = 0; q < 4; ++q) {
            int col = q * 512 + j;
            float s = bih[col] + bhh[col];
            #pragma unroll
            for (int kc = 0; kc < 3; ++kc) s += part[((size_t)kc * BB + b) * 2048 + col];
            g[q] = s;
        }
        float gi = sigm(g[0]), gf = sigm(g[1]), gg = tanh_f(g[2]), go = sigm(g[3]);
        float cold = c[b * 512 + j];
        float cn = gf * cold + gi * gg;
        c[b * 512 + j] = msk ? cn : cold;
        hs[j] = go * tanh_f(cn);
    }
    __syncthreads();
    int lane = tid & 63, wid = tid >> 6;
    for (int m = wid * 32; m < wid * 32 + 32; ++m) {
        const float* r = memB + (size_t)m * 512 + lane * 8;
        float4 r0 = *(const float4*)(r);
        float4 r1 = *(const float4*)(r + 4);
        float4 h0 = *(const float4*)(&hs[lane * 8]);
        float4 h1 = *(const float4*)(&hs[lane * 8 + 4]);
        float s = r0.x * h0.x + r0.y * h0.y + r0.z * h0.z + r0.w * h0.w
                + r1.x * h1.x + r1.y * h1.y + r1.z * h1.z + r1.w * h1.w;
        #pragma unroll
        for (int off = 32; off; off >>= 1) s += __shfl_down(s, off);
        if (lane == 0) sims[m] = s;
    }
    __syncthreads();
    float v = (tid < 128) ? sims[tid] : -3.4e38f;
    red[tid] = v; __syncthreads();
    for (int s = 128; s; s >>= 1) { if (tid < s) red[tid] = fmaxf(red[tid], red[tid + s]); __syncthreads(); }
    float mx = red[0]; __syncthreads();
    float ev = (tid < 128) ? __expf(v - mx) : 0.f;
    red[tid] = ev; __syncthreads();
    for (int s = 128; s; s >>= 1) { if (tid < s) red[tid] += red[tid + s]; __syncthreads(); }
    if (tid < 128) ps[tid] = ev / red[0];
    __syncthreads();
    for (int d = tid; d < 512; d += 256) {
        float s = 0.f;
        #pragma unroll 4
        for (int m = 0; m < 128; ++m) s += ps[m] * memB[(size_t)m * 512 + d];
        float hn = hs[d] + s;
        histB[((size_t)t * BB + b) * 512 + d] = f2bf(hn);
        float hold = h[b * 512 + d];
        float hv = msk ? hn : hold;
        h[b * 512 + d] = hv;
        hB[b * 512 + d] = f2bf(hv);
    }
}

// batched preds: hist(21*64 x 512) @ WfcT^T + bfc, masked. grid (40, 21)
__global__ __launch_bounds__(256) void k_preds_batch(const ushort* __restrict__ histB,
        const ushort* __restrict__ WfcT, const float* __restrict__ bfc,
        const int* __restrict__ lens, float* __restrict__ out) {
    __shared__ alignas(16) ushort As[64 * 64];
    __shared__ alignas(16) ushort Bs[256 * 64];
    const int n0 = blockIdx.x * 256;
    const int t = blockIdx.y;
    const ushort* A = histB + (size_t)t * BB * 512;
    const int tid = threadIdx.x, wid = tid >> 6, lane = tid & 63;
    f32x4 acc[4][4] = {};
    for (int k0 = 0; k0 < 512; k0 += 64) {
        #pragma unroll
        for (int p = 0; p < 2; ++p) {
            int c = p * 256 + tid;
            int r = c >> 3, cc = c & 7;
            float4 v = *(const float4*)(A + r * 512 + k0 + cc * 8);
            *(float4*)(As + r * 64 + ((cc ^ (r & 7)) * 8)) = v;
        }
        #pragma unroll
        for (int p = 0; p < 8; ++p) {
            int c = p * 256 + tid;
            int r = c >> 3, cc = c & 7;
            float4 v = *(const float4*)(WfcT + (size_t)(n0 + r) * 512 + k0 + cc * 8);
            *(float4*)(Bs + r * 64 + ((cc ^ (r & 7)) * 8)) = v;
        }
        __syncthreads();
        #pragma unroll
        for (int kk = 0; kk < 2; ++kk) {
            int ci = kk * 4 + (lane >> 4);
            bf16x8 afrag[4], bfrag[4];
            #pragma unroll
            for (int m = 0; m < 4; ++m) {
                int row = m * 16 + (lane & 15);
                afrag[m] = *(const bf16x8*)(As + row * 64 + ((ci ^ (row & 7)) * 8));
            }
            #pragma unroll
            for (int n = 0; n < 4; ++n) {
                int col = wid * 64 + n * 16 + (lane & 15);
                bfrag[n] = *(const bf16x8*)(Bs + col * 64 + ((ci ^ (col & 7)) * 8));
            }
            #pragma unroll
            for (int m = 0; m < 4; ++m)
                #pragma unroll
                for (int n = 0; n < 4; ++n)
                    acc[m][n] = __builtin_amdgcn_mfma_f32_16x16x32_bf16(afrag[m], bfrag[n], acc[m][n], 0, 0, 0);
        }
        __syncthreads();
    }
    #pragma unroll
    for (int m = 0; m < 4; ++m) {
        int rb = m * 16 + (lane >> 4) * 4;
        #pragma unroll
        for (int n = 0; n < 4; ++n) {
            int col = n0 + wid * 64 + n * 16 + (lane & 15);
            if (col < VV) {
                float bv = bfc[col];
                #pragma unroll
                for (int r = 0; r < 4; ++r) {
                    int b = rb + r;
                    bool msk = t < (lens[b] - 1);
                    out[((size_t)b * TT + t) * VV + col] = msk ? (acc[m][n][r] + bv) : 0.f;
                }
            }
        }
    }
}

// ---------------- launch ----------------

extern "C" void kernel_launch(void* const* d_in, const int* in_sizes, int n_in,
                              void* d_out, int out_size, void* d_ws, size_t ws_size,
                              hipStream_t stream) {
    const float* enc     = (const float*)d_in[0];
    const int*   caps    = (const int*)d_in[1];
    const int*   lens    = (const int*)d_in[2];
    const float* emb     = (const float*)d_in[3];
    const float* W_enc   = (const float*)d_in[4];
    const float* b_enc   = (const float*)d_in[5];
    const float* W_dec   = (const float*)d_in[6];
    const float* b_dec   = (const float*)d_in[7];
    const float* W_full  = (const float*)d_in[8];
    const float* W_inith = (const float*)d_in[10];
    const float* b_inith = (const float*)d_in[11];
    const float* W_initc = (const float*)d_in[12];
    const float* b_initc = (const float*)d_in[13];
    const float* W_beta  = (const float*)d_in[14];
    const float* b_beta  = (const float*)d_in[15];
    const float* W_ih    = (const float*)d_in[16];
    const float* b_ih    = (const float*)d_in[17];
    const float* W_hh    = (const float*)d_in[18];
    const float* b_hh    = (const float*)d_in[19];
    const float* memB    = (const float*)d_in[20];
    const float* W_fc    = (const float*)d_in[21];
    const float* b_fc    = (const float*)d_in[22];

    float* out = (float*)d_out;
    float* preds_out  = out;
    float* declen_out = out + (size_t)BB * TT * VV;
    float* alpha_out  = declen_out + BB;

    float* ws    = (float*)d_ws;
    ushort* att1B = (ushort*)ws;        ws += (size_t)12544 * 512 / 2;
    float* h     = ws;  ws += BB * DECD;
    float* c     = ws;  ws += BB * DECD;
    float* att2  = ws;  ws += BB * 512;
    float* gate  = ws;  ws += BB * ENCD;
    float* alpha = ws;  ws += BB * PP;
    float* part  = ws;  ws += (size_t)3 * BB * 2048;   // also ipart (8*64*512) at setup
    ushort* hB   = (ushort*)ws;  ws += BB * DECD / 2;
    uint*  aweB  = (uint*)ws;    ws += BB * ENCD / 2;
    ushort* histB = (ushort*)ws; ws += (size_t)TT * BB * DECD / 2;
    ushort* encB  = (ushort*)ws; ws += (size_t)12544 * 2048 / 2;
    ushort* WencT = (ushort*)ws; ws += (size_t)512 * 2048 / 2;
    ushort* WfcT  = (ushort*)ws; ws += (size_t)10240 * 512 / 2;
    ushort* WdecT = (ushort*)ws; ws += (size_t)512 * 512 / 2;
    ushort* WbetaT= (ushort*)ws; ws += (size_t)2048 * 512 / 2;
    ushort* WhhT  = (ushort*)ws; ws += (size_t)2048 * 512 / 2;
    ushort* WihT  = (ushort*)ws; ws += (size_t)2048 * KIH / 2;
    float* ipart = part;
    // mean aliased into att1B region (dead before k_att1_wide writes att1B)
    float* mean = (float*)att1B;

    k_mean<<<512, 256, 0, stream>>>(enc, mean);
    k_ipart<<<dim3(8, 4, 2), 256, 0, stream>>>(mean, W_inith, W_initc, ipart);
    k_ifin<<<256, 256, 0, stream>>>(ipart, b_inith, b_initc, h, c, hB);
    k_declen<<<1, 64, 0, stream>>>(lens, declen_out);
    k_cvt<<<(12544 * 2048 / 4 + 255) / 256, 256, 0, stream>>>(enc, encB, 12544 * 2048 / 4);
    k_tcvt_all<<<3392, 256, 0, stream>>>(W_enc, W_dec, W_beta, W_hh, W_ih, W_fc,
                                         WencT, WdecT, WbetaT, WhhT, WihT, WfcT);
    k_att1_wide<<<196, 512, 0, stream>>>(encB, WencT, b_enc, att1B);

    for (int t = 0; t < TT; ++t) {
        k_hgemm<<<18, 256, 0, stream>>>(hB, emb, caps, t, WdecT, b_dec, WbetaT, b_beta,
                                        WhhT, WihT, att2, gate, part);
        k_escore<<<64, 256, 0, stream>>>(att1B, att2, W_full, lens, t, alpha, alpha_out);
        k_awe16<<<dim3(4, 64), 256, 0, stream>>>(encB, alpha, gate, aweB);
        k_gawe<<<dim3(8, 2), 256, 0, stream>>>((const ushort*)aweB, WihT, part);
        k_memattn<<<64, 256, 0, stream>>>(part, b_ih, b_hh, lens, t, memB, h, c, hB, histB);
    }
    k_preds_batch<<<dim3(40, TT), 256, 0, stream>>>(histB, WfcT, b_fc, lens, preds_out);
}

// Round 6
// 1964.787 us; speedup vs baseline: 4.0401x; 1.8683x over previous
//
#include <hip/hip_runtime.h>

#define BB   64
#define PP   196
#define ENCD 2048
#define DECD 512
#define VV   10000
#define TT   21
#define KIH  2560   // (EMB + ENC) rows of W_ih

typedef __attribute__((ext_vector_type(8))) short bf16x8;
typedef __attribute__((ext_vector_type(4))) float f32x4;

__device__ __forceinline__ float sigm(float x)   { return 1.f / (1.f + __expf(-x)); }
__device__ __forceinline__ float tanh_f(float x) { return 1.f - 2.f / (1.f + __expf(2.f * x)); }
__device__ __forceinline__ ushort f2bf(float x) {
    unsigned u = __float_as_uint(x);
    unsigned r = (u + 0x7FFFu + ((u >> 16) & 1u)) >> 16;
    return (ushort)r;
}
__device__ __forceinline__ float bf2f(short u) {
    return __uint_as_float(((unsigned)(ushort)u) << 16);
}
union U8 { float4 f4; ushort u[8]; };

// ---------------- setup kernels ----------------

// f32->bf16 elementwise
__global__ void k_cvt(const float* __restrict__ in, ushort* __restrict__ out, int n4) {
    int i = blockIdx.x * 256 + threadIdx.x;
    if (i >= n4) return;
    float4 v = ((const float4*)in)[i];
    ushort4 o; o.x = f2bf(v.x); o.y = f2bf(v.y); o.z = f2bf(v.z); o.w = f2bf(v.w);
    ((ushort4*)out)[i] = o;
}

// mean over P from bf16 encoder
__global__ void k_mean16(const ushort* __restrict__ encB, float* __restrict__ mean) {
    int idx = blockIdx.x * 256 + threadIdx.x;   // 64*1024 pair-slots
    int b = idx >> 10, e2 = idx & 1023;
    const uint* p = (const uint*)encB + (size_t)b * PP * 1024 + e2;
    float s0 = 0.f, s1 = 0.f;
    #pragma unroll 7
    for (int i = 0; i < PP; ++i) {
        uint v = p[(size_t)i * 1024];
        s0 += __uint_as_float(v << 16);
        s1 += __uint_as_float(v & 0xffff0000u);
    }
    mean[b * 2048 + e2 * 2]     = s0 * (1.f / 196.f);
    mean[b * 2048 + e2 * 2 + 1] = s1 * (1.f / 196.f);
}

// h0/c0 partial GEMM (f32): grid (8 ntiles, 4 kc, 2 mat), tile 64x64
__global__ __launch_bounds__(256) void k_ipart(const float* __restrict__ mean,
        const float* __restrict__ Wh, const float* __restrict__ Wc,
        float* __restrict__ ipart) {
    __shared__ alignas(16) float As[32][68];
    __shared__ alignas(16) float Bs[32][68];
    const int n0 = blockIdx.x * 64;
    const int kc = blockIdx.y;
    const int mat = blockIdx.z;
    const float* Bp = mat ? Wc : Wh;
    const int tid = threadIdx.x, tx = tid & 15, ty = tid >> 4;
    float acc[4][4] = {};
    for (int k0 = 0; k0 < 512; k0 += 32) {
        #pragma unroll
        for (int p = 0; p < 2; ++p) {
            int c = p * 256 + tid;
            int m = c >> 3, k4 = (c & 7) * 4;
            float4 v = *(const float4*)(mean + m * 2048 + kc * 512 + k0 + k4);
            As[k4 + 0][m] = v.x; As[k4 + 1][m] = v.y; As[k4 + 2][m] = v.z; As[k4 + 3][m] = v.w;
            int kb = c >> 4, n4 = (c & 15) * 4;
            float4 w = *(const float4*)(Bp + (size_t)(kc * 512 + k0 + kb) * 512 + n0 + n4);
            *(float4*)&Bs[kb][n4] = w;
        }
        __syncthreads();
        #pragma unroll 8
        for (int k = 0; k < 32; ++k) {
            float4 a = *(const float4*)&As[k][ty * 4];
            float4 b = *(const float4*)&Bs[k][tx * 4];
            float av[4] = {a.x, a.y, a.z, a.w}, bv[4] = {b.x, b.y, b.z, b.w};
            #pragma unroll
            for (int i = 0; i < 4; ++i)
                #pragma unroll
                for (int j = 0; j < 4; ++j) acc[i][j] += av[i] * bv[j];
        }
        __syncthreads();
    }
    #pragma unroll
    for (int i = 0; i < 4; ++i) {
        int m = ty * 4 + i;
        #pragma unroll
        for (int j = 0; j < 4; ++j) {
            int n = n0 + tx * 4 + j;
            ipart[((size_t)(mat * 4 + kc) * BB + m) * 512 + n] = acc[i][j];
        }
    }
}

__global__ void k_ifin(const float* __restrict__ ipart,
                       const float* __restrict__ bh, const float* __restrict__ bc,
                       float* __restrict__ h, float* __restrict__ c, ushort* __restrict__ hB) {
    int idx = blockIdx.x * 256 + threadIdx.x;     // 2*64*512
    int mat = idx >> 15, rem = idx & 32767;
    int b = rem >> 9, d = rem & 511;
    float s = 0.f;
    #pragma unroll
    for (int kc = 0; kc < 4; ++kc) s += ipart[((size_t)(mat * 4 + kc) * BB + b) * 512 + d];
    if (mat) c[rem] = s + bc[d];
    else { float v = s + bh[d]; h[rem] = v; hB[rem] = f2bf(v); }
}

// all weight transposes in one launch: in[K][N] f32 -> out[Npad][K] bf16
__global__ __launch_bounds__(256) void k_tcvt_all(
        const float* __restrict__ Wenc, const float* __restrict__ Wdec,
        const float* __restrict__ Wbeta, const float* __restrict__ Whh,
        const float* __restrict__ Wih, const float* __restrict__ Wfc,
        ushort* __restrict__ WencT, ushort* __restrict__ WdecT,
        ushort* __restrict__ WbetaT, ushort* __restrict__ WhhT,
        ushort* __restrict__ WihT, ushort* __restrict__ WfcT) {
    __shared__ float lds[64 * 65];
    int l = blockIdx.x;
    const float* in; ushort* out; int K, N, KT;
    if (l < 256)       { in = Wenc;  out = WencT;  K = 2048; N = 512;   KT = 32; }
    else if (l < 320)  { l -= 256;  in = Wdec;  out = WdecT;  K = 512;  N = 512;   KT = 8; }
    else if (l < 576)  { l -= 320;  in = Wbeta; out = WbetaT; K = 512;  N = 2048;  KT = 8; }
    else if (l < 832)  { l -= 576;  in = Whh;   out = WhhT;   K = 512;  N = 2048;  KT = 8; }
    else if (l < 2112) { l -= 832;  in = Wih;   out = WihT;   K = KIH;  N = 2048;  KT = 40; }
    else               { l -= 2112; in = Wfc;   out = WfcT;   K = 512;  N = 10000; KT = 8; }
    const int k0 = (l % KT) * 64, n0 = (l / KT) * 64;
    const int tid = threadIdx.x;
    for (int i = tid; i < 4096; i += 256) {
        int kk = i >> 6, nn = i & 63;
        float v = 0.f;
        if (n0 + nn < N) v = in[(size_t)(k0 + kk) * N + n0 + nn];
        lds[nn * 65 + kk] = v;
    }
    __syncthreads();
    for (int i = tid; i < 4096; i += 256) {
        int nn = i >> 6, kk = i & 63;
        out[(size_t)(n0 + nn) * K + k0 + kk] = f2bf(lds[nn * 65 + kk]);
    }
}

// att1B = bf16(encB @ WencT^T + bias). tile M=64 x N=256, grid (2, 196), K=2048
__global__ __launch_bounds__(256) void k_att1_256(const ushort* __restrict__ A,
        const ushort* __restrict__ Bt, const float* __restrict__ bias,
        ushort* __restrict__ C) {
    __shared__ alignas(16) ushort As[64 * 64];
    __shared__ alignas(16) ushort Bs[256 * 64];
    const int n0 = blockIdx.x * 256;
    const int m0 = blockIdx.y * 64;
    const int tid = threadIdx.x, wid = tid >> 6, lane = tid & 63;
    f32x4 acc[4][4] = {};
    for (int k0 = 0; k0 < 2048; k0 += 64) {
        #pragma unroll
        for (int p = 0; p < 2; ++p) {
            int c = p * 256 + tid;
            int r = c >> 3, cc = c & 7;
            float4 v = *(const float4*)(A + (size_t)(m0 + r) * 2048 + k0 + cc * 8);
            *(float4*)(As + r * 64 + ((cc ^ (r & 7)) * 8)) = v;
        }
        #pragma unroll
        for (int p = 0; p < 8; ++p) {
            int c = p * 256 + tid;
            int r = c >> 3, cc = c & 7;
            float4 v = *(const float4*)(Bt + (size_t)(n0 + r) * 2048 + k0 + cc * 8);
            *(float4*)(Bs + r * 64 + ((cc ^ (r & 7)) * 8)) = v;
        }
        __syncthreads();
        #pragma unroll
        for (int kk = 0; kk < 2; ++kk) {
            int ci = kk * 4 + (lane >> 4);
            bf16x8 afrag[4], bfrag[4];
            #pragma unroll
            for (int m = 0; m < 4; ++m) {
                int row = m * 16 + (lane & 15);
                afrag[m] = *(const bf16x8*)(As + row * 64 + ((ci ^ (row & 7)) * 8));
            }
            #pragma unroll
            for (int n = 0; n < 4; ++n) {
                int col = wid * 64 + n * 16 + (lane & 15);
                bfrag[n] = *(const bf16x8*)(Bs + col * 64 + ((ci ^ (col & 7)) * 8));
            }
            #pragma unroll
            for (int m = 0; m < 4; ++m)
                #pragma unroll
                for (int n = 0; n < 4; ++n)
                    acc[m][n] = __builtin_amdgcn_mfma_f32_16x16x32_bf16(afrag[m], bfrag[n], acc[m][n], 0, 0, 0);
        }
        __syncthreads();
    }
    #pragma unroll
    for (int m = 0; m < 4; ++m) {
        int rb = m0 + m * 16 + (lane >> 4) * 4;
        #pragma unroll
        for (int n = 0; n < 4; ++n) {
            int col = n0 + wid * 64 + n * 16 + (lane & 15);
            float bv = bias[col];
            #pragma unroll
            for (int r = 0; r < 4; ++r)
                C[(size_t)(rb + r) * 512 + col] = f2bf(acc[m][n][r] + bv);
        }
    }
}

__global__ void k_declen(const int* __restrict__ lens, float* __restrict__ out) {
    int b = threadIdx.x;
    if (b < BB) out[b] = (float)(lens[b] - 1);
}

// ---------------- per-step kernels ----------------

// P1: tile 64x64, 72 blocks.
// bx 0-7:   att2 = h@W_dec + bd            (K=512)
// bx 8-39:  gate = sigm(h@W_beta + bb)     (K=512)
// bx 40-71: hhp  = h@W_hh + emb@W_ih[0:512] (K=1024 fused)
__global__ __launch_bounds__(256) void k_hgemm64(const ushort* __restrict__ hB,
        const float* __restrict__ emb, const int* __restrict__ caps, int t,
        const ushort* __restrict__ WdecT, const float* __restrict__ bd,
        const ushort* __restrict__ WbetaT, const float* __restrict__ bb,
        const ushort* __restrict__ WhhT, const ushort* __restrict__ WihT,
        float* __restrict__ att2, float* __restrict__ gate, float* __restrict__ hhp) {
    __shared__ alignas(16) ushort As[64 * 64];
    __shared__ alignas(16) ushort Bs[64 * 64];
    __shared__ int capsh[64];
    const int bx = blockIdx.x;
    int seg, n0;
    if (bx < 8)       { seg = 0; n0 = bx * 64; }
    else if (bx < 40) { seg = 1; n0 = (bx - 8) * 64; }
    else              { seg = 2; n0 = (bx - 40) * 64; }
    const int tid = threadIdx.x, wid = tid >> 6, lane = tid & 63;
    if (tid < 64) capsh[tid] = caps[tid * 22 + t];
    __syncthreads();
    const int KSEG = (seg == 2) ? 1024 : 512;
    f32x4 acc[4] = {};
    for (int k0 = 0; k0 < KSEG; k0 += 64) {
        const bool second = k0 >= 512;
        #pragma unroll
        for (int p = 0; p < 2; ++p) {
            int c = p * 256 + tid;
            int r = c >> 3, cc = c & 7;
            if (!second) {
                float4 v = *(const float4*)(hB + r * 512 + k0 + cc * 8);
                *(float4*)(As + r * 64 + ((cc ^ (r & 7)) * 8)) = v;
            } else {
                const float* er = emb + (size_t)capsh[r] * 512 + (k0 - 512) + cc * 8;
                float4 v0 = *(const float4*)er;
                float4 v1 = *(const float4*)(er + 4);
                U8 pk;
                pk.u[0] = f2bf(v0.x); pk.u[1] = f2bf(v0.y); pk.u[2] = f2bf(v0.z); pk.u[3] = f2bf(v0.w);
                pk.u[4] = f2bf(v1.x); pk.u[5] = f2bf(v1.y); pk.u[6] = f2bf(v1.z); pk.u[7] = f2bf(v1.w);
                *(float4*)(As + r * 64 + ((cc ^ (r & 7)) * 8)) = pk.f4;
            }
            const ushort* brow;
            if (seg == 0)      brow = WdecT + (size_t)(n0 + r) * 512 + k0 + cc * 8;
            else if (seg == 1) brow = WbetaT + (size_t)(n0 + r) * 512 + k0 + cc * 8;
            else brow = second ? (WihT + (size_t)(n0 + r) * KIH + (k0 - 512) + cc * 8)
                               : (WhhT + (size_t)(n0 + r) * 512 + k0 + cc * 8);
            float4 v = *(const float4*)brow;
            *(float4*)(Bs + r * 64 + ((cc ^ (r & 7)) * 8)) = v;
        }
        __syncthreads();
        #pragma unroll
        for (int kk = 0; kk < 2; ++kk) {
            int ci = kk * 4 + (lane >> 4);
            int colL = wid * 16 + (lane & 15);
            bf16x8 bfrag = *(const bf16x8*)(Bs + colL * 64 + ((ci ^ (colL & 7)) * 8));
            #pragma unroll
            for (int m = 0; m < 4; ++m) {
                int row = m * 16 + (lane & 15);
                bf16x8 afrag = *(const bf16x8*)(As + row * 64 + ((ci ^ (row & 7)) * 8));
                acc[m] = __builtin_amdgcn_mfma_f32_16x16x32_bf16(afrag, bfrag, acc[m], 0, 0, 0);
            }
        }
        __syncthreads();
    }
    int colL = wid * 16 + (lane & 15);
    int col = n0 + colL;
    #pragma unroll
    for (int m = 0; m < 4; ++m) {
        int rb = m * 16 + (lane >> 4) * 4;
        #pragma unroll
        for (int r = 0; r < 4; ++r) {
            int row = rb + r;
            float v = acc[m][r];
            if (seg == 0)      att2[row * 512 + col] = v + bd[col];
            else if (seg == 1) gate[row * 2048 + col] = sigm(v + bb[col]);
            else               hhp[(size_t)row * 2048 + col] = v;
        }
    }
}

// e-score dot products, grid (4 p-chunks, 64 b)
__global__ __launch_bounds__(256) void k_escore_p(const ushort* __restrict__ att1B,
        const float* __restrict__ att2, const float* __restrict__ Wf,
        float* __restrict__ es) {
    __shared__ float a2[512], wf[512];
    int b = blockIdx.y, pc = blockIdx.x, tid = threadIdx.x;
    for (int i = tid; i < 512; i += 256) { a2[i] = att2[b * 512 + i]; wf[i] = Wf[i]; }
    __syncthreads();
    int lane = tid & 63, wid = tid >> 6;
    for (int i = wid; i < 49; i += 4) {
        int p = pc * 49 + i;
        bf16x8 rv = *(const bf16x8*)(att1B + ((size_t)(b * PP + p)) * 512 + lane * 8);
        float s = 0.f;
        #pragma unroll
        for (int j = 0; j < 8; ++j) {
            float v = bf2f(rv[j]) + a2[lane * 8 + j];
            s += (v > 0.f ? v : 0.f) * wf[lane * 8 + j];
        }
        #pragma unroll
        for (int off = 32; off; off >>= 1) s += __shfl_down(s, off);
        if (lane == 0) es[b * 256 + p] = s;
    }
}

// softmax (local) + awe + gate + bf16 pack; grid (8 e-chunks, 64 b)
__global__ __launch_bounds__(256) void k_awe16s(const ushort* __restrict__ encB,
        const float* __restrict__ es, const float* __restrict__ gate,
        const int* __restrict__ lens, int t,
        uint* __restrict__ aweB, float* __restrict__ out_alpha) {
    __shared__ float al[224], red[256];
    int b = blockIdx.y, pc = blockIdx.x, tid = threadIdx.x;
    float v = (tid < PP) ? es[b * 256 + tid] : -3.4e38f;
    red[tid] = v; __syncthreads();
    for (int s = 128; s; s >>= 1) { if (tid < s) red[tid] = fmaxf(red[tid], red[tid + s]); __syncthreads(); }
    float mx = red[0]; __syncthreads();
    float ev = (tid < PP) ? __expf(v - mx) : 0.f;
    red[tid] = ev; __syncthreads();
    for (int s = 128; s; s >>= 1) { if (tid < s) red[tid] += red[tid + s]; __syncthreads(); }
    float inv = 1.f / red[0];
    if (tid < PP) {
        float a = ev * inv;
        al[tid] = a;
        if (pc == 0) {
            bool m = t < (lens[b] - 1);
            out_alpha[((size_t)b * TT + t) * PP + tid] = m ? a : 0.f;
        }
    }
    __syncthreads();
    // awe: this block covers pairs [pc*128, pc*128+128); 2 threads per pair
    int pair = pc * 128 + (tid >> 1);
    int half = tid & 1;
    const uint* p = (const uint*)encB + (size_t)b * PP * 1024 + pair;
    float s0 = 0.f, s1 = 0.f;
    int i0 = half * 98;
    #pragma unroll 7
    for (int i = i0; i < i0 + 98; ++i) {
        uint vv = p[(size_t)i * 1024];
        float a = al[i];
        s0 += a * __uint_as_float(vv << 16);
        s1 += a * __uint_as_float(vv & 0xffff0000u);
    }
    s0 += __shfl_xor(s0, 1);
    s1 += __shfl_xor(s1, 1);
    if (half == 0) {
        int e = pair * 2;
        float g0 = s0 * gate[b * 2048 + e];
        float g1 = s1 * gate[b * 2048 + e + 1];
        aweB[b * 1024 + pair] = (uint)f2bf(g0) | ((uint)f2bf(g1) << 16);
    }
}

// pawe[kc] = aweB[:, kc*512:+512] @ W_ih[512+kc*512 ..]; grid (32 ntile, 4 kc), tile 64x64
__global__ __launch_bounds__(256) void k_gawe64(const ushort* __restrict__ aweB,
        const ushort* __restrict__ WihT, float* __restrict__ pawe) {
    __shared__ alignas(16) ushort As[64 * 64];
    __shared__ alignas(16) ushort Bs[64 * 64];
    const int n0 = blockIdx.x * 64;
    const int kc = blockIdx.y;
    const int tid = threadIdx.x, wid = tid >> 6, lane = tid & 63;
    f32x4 acc[4] = {};
    for (int k0 = 0; k0 < 512; k0 += 64) {
        #pragma unroll
        for (int p = 0; p < 2; ++p) {
            int c = p * 256 + tid;
            int r = c >> 3, cc = c & 7;
            float4 v = *(const float4*)(aweB + r * 2048 + kc * 512 + k0 + cc * 8);
            *(float4*)(As + r * 64 + ((cc ^ (r & 7)) * 8)) = v;
            float4 w = *(const float4*)(WihT + (size_t)(n0 + r) * KIH + 512 + kc * 512 + k0 + cc * 8);
            *(float4*)(Bs + r * 64 + ((cc ^ (r & 7)) * 8)) = w;
        }
        __syncthreads();
        #pragma unroll
        for (int kk = 0; kk < 2; ++kk) {
            int ci = kk * 4 + (lane >> 4);
            int colL = wid * 16 + (lane & 15);
            bf16x8 bfrag = *(const bf16x8*)(Bs + colL * 64 + ((ci ^ (colL & 7)) * 8));
            #pragma unroll
            for (int m = 0; m < 4; ++m) {
                int row = m * 16 + (lane & 15);
                bf16x8 afrag = *(const bf16x8*)(As + row * 64 + ((ci ^ (row & 7)) * 8));
                acc[m] = __builtin_amdgcn_mfma_f32_16x16x32_bf16(afrag, bfrag, acc[m], 0, 0, 0);
            }
        }
        __syncthreads();
    }
    int col = n0 + wid * 16 + (lane & 15);
    #pragma unroll
    for (int m = 0; m < 4; ++m) {
        int rb = m * 16 + (lane >> 4) * 4;
        #pragma unroll
        for (int r = 0; r < 4; ++r)
            pawe[((size_t)kc * BB + rb + r) * 2048 + col] = acc[m][r];
    }
}

// LSTM pointwise + memory attention + carry; writes h,c (masked), hB, histB
__global__ __launch_bounds__(256) void k_memattn(const float* __restrict__ hhp,
        const float* __restrict__ pawe,
        const float* __restrict__ bih, const float* __restrict__ bhh,
        const int* __restrict__ lens, int t, const float* __restrict__ memB,
        float* __restrict__ h, float* __restrict__ c,
        ushort* __restrict__ hB, ushort* __restrict__ histB) {
    __shared__ float hs[512], sims[128], red[256], ps[128];
    int b = blockIdx.x, tid = threadIdx.x;
    bool msk = t < (lens[b] - 1);
    for (int j = tid; j < 512; j += 256) {
        float g[4];
        #pragma unroll
        for (int q = 0; q < 4; ++q) {
            int col = q * 512 + j;
            float s = bih[col] + bhh[col] + hhp[(size_t)b * 2048 + col];
            #pragma unroll
            for (int kc = 0; kc < 4; ++kc) s += pawe[((size_t)kc * BB + b) * 2048 + col];
            g[q] = s;
        }
        float gi = sigm(g[0]), gf = sigm(g[1]), gg = tanh_f(g[2]), go = sigm(g[3]);
        float cold = c[b * 512 + j];
        float cn = gf * cold + gi * gg;
        c[b * 512 + j] = msk ? cn : cold;
        hs[j] = go * tanh_f(cn);
    }
    __syncthreads();
    int lane = tid & 63, wid = tid >> 6;
    for (int m = wid * 32; m < wid * 32 + 32; ++m) {
        const float* r = memB + (size_t)m * 512 + lane * 8;
        float4 r0 = *(const float4*)(r);
        float4 r1 = *(const float4*)(r + 4);
        float4 h0 = *(const float4*)(&hs[lane * 8]);
        float4 h1 = *(const float4*)(&hs[lane * 8 + 4]);
        float s = r0.x * h0.x + r0.y * h0.y + r0.z * h0.z + r0.w * h0.w
                + r1.x * h1.x + r1.y * h1.y + r1.z * h1.z + r1.w * h1.w;
        #pragma unroll
        for (int off = 32; off; off >>= 1) s += __shfl_down(s, off);
        if (lane == 0) sims[m] = s;
    }
    __syncthreads();
    float v = (tid < 128) ? sims[tid] : -3.4e38f;
    red[tid] = v; __syncthreads();
    for (int s = 128; s; s >>= 1) { if (tid < s) red[tid] = fmaxf(red[tid], red[tid + s]); __syncthreads(); }
    float mx = red[0]; __syncthreads();
    float ev = (tid < 128) ? __expf(v - mx) : 0.f;
    red[tid] = ev; __syncthreads();
    for (int s = 128; s; s >>= 1) { if (tid < s) red[tid] += red[tid + s]; __syncthreads(); }
    if (tid < 128) ps[tid] = ev / red[0];
    __syncthreads();
    for (int d = tid; d < 512; d += 256) {
        float s = 0.f;
        #pragma unroll 4
        for (int m = 0; m < 128; ++m) s += ps[m] * memB[(size_t)m * 512 + d];
        float hn = hs[d] + s;
        histB[((size_t)t * BB + b) * 512 + d] = f2bf(hn);
        float hold = h[b * 512 + d];
        float hv = msk ? hn : hold;
        h[b * 512 + d] = hv;
        hB[b * 512 + d] = f2bf(hv);
    }
}

// batched preds: hist(21*64 x 512) @ WfcT^T + bfc, masked. grid (40, 21)
__global__ __launch_bounds__(256) void k_preds_batch(const ushort* __restrict__ histB,
        const ushort* __restrict__ WfcT, const float* __restrict__ bfc,
        const int* __restrict__ lens, float* __restrict__ out) {
    __shared__ alignas(16) ushort As[64 * 64];
    __shared__ alignas(16) ushort Bs[256 * 64];
    const int n0 = blockIdx.x * 256;
    const int t = blockIdx.y;
    const ushort* A = histB + (size_t)t * BB * 512;
    const int tid = threadIdx.x, wid = tid >> 6, lane = tid & 63;
    f32x4 acc[4][4] = {};
    for (int k0 = 0; k0 < 512; k0 += 64) {
        #pragma unroll
        for (int p = 0; p < 2; ++p) {
            int c = p * 256 + tid;
            int r = c >> 3, cc = c & 7;
            float4 v = *(const float4*)(A + r * 512 + k0 + cc * 8);
            *(float4*)(As + r * 64 + ((cc ^ (r & 7)) * 8)) = v;
        }
        #pragma unroll
        for (int p = 0; p < 8; ++p) {
            int c = p * 256 + tid;
            int r = c >> 3, cc = c & 7;
            float4 v = *(const float4*)(WfcT + (size_t)(n0 + r) * 512 + k0 + cc * 8);
            *(float4*)(Bs + r * 64 + ((cc ^ (r & 7)) * 8)) = v;
        }
        __syncthreads();
        #pragma unroll
        for (int kk = 0; kk < 2; ++kk) {
            int ci = kk * 4 + (lane >> 4);
            bf16x8 afrag[4], bfrag[4];
            #pragma unroll
            for (int m = 0; m < 4; ++m) {
                int row = m * 16 + (lane & 15);
                afrag[m] = *(const bf16x8*)(As + row * 64 + ((ci ^ (row & 7)) * 8));
            }
            #pragma unroll
            for (int n = 0; n < 4; ++n) {
                int col = wid * 64 + n * 16 + (lane & 15);
                bfrag[n] = *(const bf16x8*)(Bs + col * 64 + ((ci ^ (col & 7)) * 8));
            }
            #pragma unroll
            for (int m = 0; m < 4; ++m)
                #pragma unroll
                for (int n = 0; n < 4; ++n)
                    acc[m][n] = __builtin_amdgcn_mfma_f32_16x16x32_bf16(afrag[m], bfrag[n], acc[m][n], 0, 0, 0);
        }
        __syncthreads();
    }
    #pragma unroll
    for (int m = 0; m < 4; ++m) {
        int rb = m * 16 + (lane >> 4) * 4;
        #pragma unroll
        for (int n = 0; n < 4; ++n) {
            int col = n0 + wid * 64 + n * 16 + (lane & 15);
            if (col < VV) {
                float bv = bfc[col];
                #pragma unroll
                for (int r = 0; r < 4; ++r) {
                    int b = rb + r;
                    bool msk = t < (lens[b] - 1);
                    out[((size_t)b * TT + t) * VV + col] = msk ? (acc[m][n][r] + bv) : 0.f;
                }
            }
        }
    }
}

// ---------------- launch ----------------

extern "C" void kernel_launch(void* const* d_in, const int* in_sizes, int n_in,
                              void* d_out, int out_size, void* d_ws, size_t ws_size,
                              hipStream_t stream) {
    const float* enc     = (const float*)d_in[0];
    const int*   caps    = (const int*)d_in[1];
    const int*   lens    = (const int*)d_in[2];
    const float* emb     = (const float*)d_in[3];
    const float* W_enc   = (const float*)d_in[4];
    const float* b_enc   = (const float*)d_in[5];
    const float* W_dec   = (const float*)d_in[6];
    const float* b_dec   = (const float*)d_in[7];
    const float* W_full  = (const float*)d_in[8];
    const float* W_inith = (const float*)d_in[10];
    const float* b_inith = (const float*)d_in[11];
    const float* W_initc = (const float*)d_in[12];
    const float* b_initc = (const float*)d_in[13];
    const float* W_beta  = (const float*)d_in[14];
    const float* b_beta  = (const float*)d_in[15];
    const float* W_ih    = (const float*)d_in[16];
    const float* b_ih    = (const float*)d_in[17];
    const float* W_hh    = (const float*)d_in[18];
    const float* b_hh    = (const float*)d_in[19];
    const float* memB    = (const float*)d_in[20];
    const float* W_fc    = (const float*)d_in[21];
    const float* b_fc    = (const float*)d_in[22];

    float* out = (float*)d_out;
    float* preds_out  = out;
    float* declen_out = out + (size_t)BB * TT * VV;
    float* alpha_out  = declen_out + BB;

    float* ws    = (float*)d_ws;
    ushort* att1B = (ushort*)ws;        ws += (size_t)12544 * 512 / 2;
    float* h     = ws;  ws += BB * DECD;
    float* c     = ws;  ws += BB * DECD;
    float* att2  = ws;  ws += BB * 512;
    float* gate  = ws;  ws += BB * ENCD;
    float* es    = ws;  ws += BB * 256;
    float* hhp   = ws;  ws += BB * 2048;
    float* pawe  = ws;  ws += (size_t)4 * BB * 2048;
    ushort* hB   = (ushort*)ws;  ws += BB * DECD / 2;
    uint*  aweB  = (uint*)ws;    ws += BB * ENCD / 2;
    ushort* histB = (ushort*)ws; ws += (size_t)TT * BB * DECD / 2;
    ushort* encB  = (ushort*)ws; ws += (size_t)12544 * 2048 / 2;
    ushort* WencT = (ushort*)ws; ws += (size_t)512 * 2048 / 2;
    ushort* WfcT  = (ushort*)ws; ws += (size_t)10240 * 512 / 2;
    ushort* WdecT = (ushort*)ws; ws += (size_t)512 * 512 / 2;
    ushort* WbetaT= (ushort*)ws; ws += (size_t)2048 * 512 / 2;
    ushort* WhhT  = (ushort*)ws; ws += (size_t)2048 * 512 / 2;
    ushort* WihT  = (ushort*)ws; ws += (size_t)2048 * KIH / 2;
    // aliases (setup-only, dead before their regions are written)
    float* ipart = hhp;              // needs 8*64*512 f32 = hhp+pawe region
    float* mean  = (float*)att1B;    // dead before k_att1_256 writes att1B

    k_cvt<<<(12544 * 2048 / 4 + 255) / 256, 256, 0, stream>>>(enc, encB, 12544 * 2048 / 4);
    k_mean16<<<256, 256, 0, stream>>>(encB, mean);
    k_ipart<<<dim3(8, 4, 2), 256, 0, stream>>>(mean, W_inith, W_initc, ipart);
    k_ifin<<<256, 256, 0, stream>>>(ipart, b_inith, b_initc, h, c, hB);
    k_declen<<<1, 64, 0, stream>>>(lens, declen_out);
    k_tcvt_all<<<3392, 256, 0, stream>>>(W_enc, W_dec, W_beta, W_hh, W_ih, W_fc,
                                         WencT, WdecT, WbetaT, WhhT, WihT, WfcT);
    k_att1_256<<<dim3(2, 196), 256, 0, stream>>>(encB, WencT, b_enc, att1B);

    for (int t = 0; t < TT; ++t) {
        k_hgemm64<<<72, 256, 0, stream>>>(hB, emb, caps, t, WdecT, b_dec, WbetaT, b_beta,
                                          WhhT, WihT, att2, gate, hhp);
        k_escore_p<<<dim3(4, 64), 256, 0, stream>>>(att1B, att2, W_full, es);
        k_awe16s<<<dim3(8, 64), 256, 0, stream>>>(encB, es, gate, lens, t, aweB, alpha_out);
        k_gawe64<<<dim3(32, 4), 256, 0, stream>>>((const ushort*)aweB, WihT, pawe);
        k_memattn<<<64, 256, 0, stream>>>(hhp, pawe, b_ih, b_hh, lens, t, memB, h, c, hB, histB);
    }
    k_preds_batch<<<dim3(40, TT), 256, 0, stream>>>(histB, WfcT, b_fc, lens, preds_out);
}